// Round 1
// baseline (1604.028 us; speedup 1.0000x reference)
//
#include <hip/hip_runtime.h>

#define N_NODES 20000
#define D_IN    1000
#define E_EDGES 160000
#define DA      100

#define MP   20096    // 157 * 128 (padded rows)
#define DP   1024     // padded K / structural cols
#define DAP  128      // padded attr cols
#define MBLK 157

typedef __bf16 bf16x8 __attribute__((ext_vector_type(8)));
typedef float  f32x4  __attribute__((ext_vector_type(4)));

__device__ __forceinline__ short f2bf(float f) {
  unsigned u = __float_as_uint(f);
  return (short)((u + 0x7FFFu + ((u >> 16) & 1u)) >> 16);   // RNE
}
__device__ __forceinline__ float bf2f(short s) {
  return __uint_as_float(((unsigned)(unsigned short)s) << 16);
}

#define GLDS16(g, l) __builtin_amdgcn_global_load_lds( \
    (const __attribute__((address_space(1))) void*)(g), \
    (__attribute__((address_space(3))) void*)(l), 16, 0, 0)

// ---------------------------------------------------------------- conversions

// dst[r*Cp + c] = bf16(src[r*C + c]) with zero padding. grid: (Cp/256, Rp)
__global__ void cvt_pad_k(const float* __restrict__ src, int R, int C,
                          short* __restrict__ dst, int Cp) {
  int r = blockIdx.y;
  int c = blockIdx.x * blockDim.x + threadIdx.x;
  float v = (r < R && c < C) ? src[(size_t)r * C + c] : 0.f;
  dst[(size_t)r * Cp + c] = f2bf(v);
}

// Wt[n*Kp + k] = bf16(W[k*Nc + n]) zero padded. grid: ((Kp+255)/256, Np)
__global__ void cvt_w_t_k(const float* __restrict__ src, int K, int Nc,
                          short* __restrict__ dst, int Kp) {
  int n = blockIdx.y;
  int k = blockIdx.x * blockDim.x + threadIdx.x;
  if (k >= Kp) return;
  float v = (k < K && n < Nc) ? src[(size_t)k * Nc + n] : 0.f;
  dst[(size_t)n * Kp + k] = f2bf(v);
}

__global__ void zero_int_k(int* p, int n) {
  int i = blockIdx.x * blockDim.x + threadIdx.x;
  if (i < n) p[i] = 0;
}

// ---------------------------------------------------------------- CSR build

__global__ void hist_k(const int* __restrict__ row, int E, int* __restrict__ offs) {
  int e = blockIdx.x * blockDim.x + threadIdx.x;
  if (e < E) atomicAdd(&offs[row[e] + 1], 1);
}

#define SCAN_T 1024
#define SCAN_C 20
__launch_bounds__(SCAN_T)
__global__ void scan_k(int* __restrict__ a, int n) {
  __shared__ int lds[SCAN_T];
  int t = threadIdx.x;
  int base = t * SCAN_C;
  int v[SCAN_C];
  int s = 0;
#pragma unroll
  for (int i = 0; i < SCAN_C; ++i) {
    int idx = base + i;
    int x = (idx < n) ? a[idx] : 0;
    s += x;
    v[i] = s;
  }
  lds[t] = s;
  __syncthreads();
  for (int off = 1; off < SCAN_T; off <<= 1) {
    int add = (t >= off) ? lds[t - off] : 0;
    __syncthreads();
    lds[t] += add;
    __syncthreads();
  }
  int prefix = lds[t] - s;
#pragma unroll
  for (int i = 0; i < SCAN_C; ++i) {
    int idx = base + i;
    if (idx < n) a[idx] = v[i] + prefix;
  }
}

__global__ void scatter_k(const int* __restrict__ row, int E,
                          const int* __restrict__ offs, int* __restrict__ cursor,
                          int* __restrict__ perm) {
  int e = blockIdx.x * blockDim.x + threadIdx.x;
  if (e < E) {
    int r = row[e];
    int p = atomicAdd(&cursor[r], 1);
    perm[offs[r] + p] = e;
  }
}

// ---------------------------------------------------------------- GEMM (bf16 MFMA)
// C[M x Nc] = A[M x K] * Wt[Nc x K]^T, all bf16, f32 accum, C written bf16.
// Tile 128x128, BK=64, 256 threads (4 waves, 2x2), wave does 64x64 = 4x4 frags.
__launch_bounds__(256, 2)
__global__ void gemm_bf16_k(const short* __restrict__ A, int lda,
                            const short* __restrict__ Bt, int ldb,
                            short* __restrict__ C, int ldc, int K) {
  __shared__ short As[128 * 64];
  __shared__ short Bs[128 * 64];

  const int tid  = threadIdx.x;
  const int lane = tid & 63;
  const int wid  = tid >> 6;
  const int wr   = wid >> 1;
  const int wc   = wid & 1;
  const int rowBase = blockIdx.x * 128;
  const int colBase = blockIdx.y * 128;

  const int lrow = lane >> 3;        // 0..7: row within an 8-row chunk
  const int kofs = (lane & 7) * 8;   // 0..56: bf16 offset within 64-col K slab

  f32x4 acc[4][4];
#pragma unroll
  for (int m = 0; m < 4; ++m)
#pragma unroll
    for (int n = 0; n < 4; ++n)
      acc[m][n] = (f32x4){0.f, 0.f, 0.f, 0.f};

  for (int k0 = 0; k0 < K; k0 += 64) {
    // stage A tile: 128 rows x 64 cols, linear [r][k]
#pragma unroll
    for (int c = 0; c < 4; ++c) {
      int chunk = wid * 4 + c;            // 0..15, 8 rows each
      int r = chunk * 8 + lrow;
      const short* g = A + (size_t)(rowBase + r) * lda + k0 + kofs;
      GLDS16(g, &As[chunk * 8 * 64]);
    }
    // stage B tile from Wt (row n, col k): same shape [128][64]
#pragma unroll
    for (int c = 0; c < 4; ++c) {
      int chunk = wid * 4 + c;
      int r = chunk * 8 + lrow;
      const short* g = Bt + (size_t)(colBase + r) * ldb + k0 + kofs;
      GLDS16(g, &Bs[chunk * 8 * 64]);
    }
    __syncthreads();

    bf16x8 af[2][4], bfr[2][4];
#pragma unroll
    for (int kk = 0; kk < 2; ++kk) {
#pragma unroll
      for (int i = 0; i < 4; ++i) {
        int ar = wr * 64 + i * 16 + (lane & 15);
        af[kk][i]  = *(const bf16x8*)&As[ar * 64 + kk * 32 + (lane >> 4) * 8];
        int br = wc * 64 + i * 16 + (lane & 15);
        bfr[kk][i] = *(const bf16x8*)&Bs[br * 64 + kk * 32 + (lane >> 4) * 8];
      }
    }
#pragma unroll
    for (int kk = 0; kk < 2; ++kk)
#pragma unroll
      for (int m = 0; m < 4; ++m)
#pragma unroll
        for (int n = 0; n < 4; ++n)
          acc[m][n] = __builtin_amdgcn_mfma_f32_16x16x32_bf16(
              af[kk][m], bfr[kk][n], acc[m][n], 0, 0, 0);
    __syncthreads();
  }

  // write C (bf16). D layout: col = lane&15, row = (lane>>4)*4 + reg
#pragma unroll
  for (int m = 0; m < 4; ++m) {
#pragma unroll
    for (int n = 0; n < 4; ++n) {
      int row0 = rowBase + wr * 64 + m * 16 + (lane >> 4) * 4;
      int col  = colBase + wc * 64 + n * 16 + (lane & 15);
#pragma unroll
      for (int reg = 0; reg < 4; ++reg)
        C[(size_t)(row0 + reg) * ldc + col] = f2bf(acc[m][n][reg]);
    }
  }
}

// ---------------------------------------------------------------- SpMM + ReLU
// out[r] = relu( sum_e vals[e] * S[col[e]] ) over CSR row r.
// grid: (n_rows, ncols/blockDim). If outB: write bf16 (stride ldB, all cols).
// Else: write f32 to outF (stride outCols, only c < outCols).
__global__ void spmm_relu_k(const int* __restrict__ offs, const int* __restrict__ perm,
                            const int* __restrict__ col, const float* __restrict__ vals,
                            const short* __restrict__ S, int ldS,
                            short* __restrict__ outB, int ldB,
                            float* __restrict__ outF, int outCols) {
  int r = blockIdx.x;
  int c = blockIdx.y * blockDim.x + threadIdx.x;
  int e0 = offs[r], e1 = offs[r + 1];
  float acc = 0.f;
  for (int i = e0; i < e1; ++i) {
    int e = perm[i];
    acc += vals[e] * bf2f(S[(size_t)col[e] * ldS + c]);
  }
  acc = fmaxf(acc, 0.f);
  if (outB) {
    outB[(size_t)r * ldB + c] = f2bf(acc);
  } else if (c < outCols) {
    outF[(size_t)r * outCols + c] = acc;
  }
}

// ---------------------------------------------------------------- row l2 norm
__global__ void l2norm_k(const short* __restrict__ H, int ldH,
                         float* __restrict__ out, int cols) {
  __shared__ float red[4];
  int r = blockIdx.x;
  int t = threadIdx.x;
  float s = 0.f;
  for (int c = t; c < ldH; c += 256) {
    float v = bf2f(H[(size_t)r * ldH + c]);
    s += v * v;
  }
  for (int off = 32; off >= 1; off >>= 1) s += __shfl_down(s, off, 64);
  if ((t & 63) == 0) red[t >> 6] = s;
  __syncthreads();
  float tot = red[0] + red[1] + red[2] + red[3];
  float inv = 1.f / fmaxf(sqrtf(tot), 1e-12f);
  for (int c = t; c < cols; c += 256)
    out[(size_t)r * cols + c] = bf2f(H[(size_t)r * ldH + c]) * inv;
}

// ---------------------------------------------------------------- launch

extern "C" void kernel_launch(void* const* d_in, const int* in_sizes, int n_in,
                              void* d_out, int out_size, void* d_ws, size_t ws_size,
                              hipStream_t stream) {
  const float* emb_sr  = (const float*)d_in[0];
  const float* emb_tg  = (const float*)d_in[1];
  const float* attr_sr = (const float*)d_in[2];
  const float* attr_tg = (const float*)d_in[3];
  const int*   row_sr  = (const int*)d_in[4];
  const int*   col_sr  = (const int*)d_in[5];
  const float* vals_sr = (const float*)d_in[6];
  const int*   row_tg  = (const int*)d_in[7];
  const int*   col_tg  = (const int*)d_in[8];
  const float* vals_tg = (const float*)d_in[9];
  const float* W_s0    = (const float*)d_in[10];
  const float* W_s1    = (const float*)d_in[11];
  const float* W_a11   = (const float*)d_in[12];
  const float* W_a12   = (const float*)d_in[13];
  const float* W_a2    = (const float*)d_in[14];

  const int N = N_NODES, Dd = D_IN, E = E_EDGES;

  // workspace layout
  char* ws = (char*)d_ws;
  size_t off = 0;
  auto alloc = [&](size_t bytes) -> void* {
    void* p = ws + off;
    off += (bytes + 255) & ~(size_t)255;
    return p;
  };
  short* B0    = (short*)alloc((size_t)MP * DP * 2);
  short* B1    = (short*)alloc((size_t)MP * DP * 2);
  short* Ws0t  = (short*)alloc((size_t)DP * DP * 2);
  short* Ws1t  = (short*)alloc((size_t)DP * DP * 2);
  short* Wa11t = (short*)alloc((size_t)DAP * DP * 2);
  short* Wa12t = (short*)alloc((size_t)DAP * DP * 2);
  short* Wa2t  = (short*)alloc((size_t)DAP * DAP * 2);
  int* offs_sr = (int*)alloc((size_t)(20004 + N) * 4);  // offs(20001)+pad+cursor(20000)
  int* offs_tg = (int*)alloc((size_t)(20004 + N) * 4);
  int* perm_sr = (int*)alloc((size_t)E * 4);
  int* perm_tg = (int*)alloc((size_t)E * 4);
  if (off > ws_size) return;  // workspace too small — fail visibly

  int* cur_sr = offs_sr + 20004;
  int* cur_tg = offs_tg + 20004;

  float* out_sr  = (float*)d_out;
  float* out_tg  = out_sr + (size_t)N * Dd;
  float* out_sra = out_tg + (size_t)N * Dd;
  float* out_tga = out_sra + (size_t)N * DA;

  // ---- CSR build for both graphs
  zero_int_k<<<dim3((20004 + N + 255) / 256), 256, 0, stream>>>(offs_sr, 20004 + N);
  zero_int_k<<<dim3((20004 + N + 255) / 256), 256, 0, stream>>>(offs_tg, 20004 + N);
  hist_k<<<dim3((E + 255) / 256), 256, 0, stream>>>(row_sr, E, offs_sr);
  hist_k<<<dim3((E + 255) / 256), 256, 0, stream>>>(row_tg, E, offs_tg);
  scan_k<<<1, SCAN_T, 0, stream>>>(offs_sr, N + 1);
  scan_k<<<1, SCAN_T, 0, stream>>>(offs_tg, N + 1);
  scatter_k<<<dim3((E + 255) / 256), 256, 0, stream>>>(row_sr, E, offs_sr, cur_sr, perm_sr);
  scatter_k<<<dim3((E + 255) / 256), 256, 0, stream>>>(row_tg, E, offs_tg, cur_tg, perm_tg);

  // ---- weight conversions (transposed + padded)
  cvt_w_t_k<<<dim3(DP / 256, DP), 256, 0, stream>>>(W_s0, Dd, Dd, Ws0t, DP);
  cvt_w_t_k<<<dim3(DP / 256, DP), 256, 0, stream>>>(W_s1, Dd, Dd, Ws1t, DP);
  cvt_w_t_k<<<dim3(DP / 256, DAP), 256, 0, stream>>>(W_a11, Dd, DA, Wa11t, DP);
  cvt_w_t_k<<<dim3(DP / 256, DAP), 256, 0, stream>>>(W_a12, Dd, DA, Wa12t, DP);
  cvt_w_t_k<<<dim3(1, DAP), 256, 0, stream>>>(W_a2, DA, DA, Wa2t, DAP);

  // ---- per-graph pipelines
  struct G {
    const float *emb, *attr, *vals;
    const int *col;
    const short *Wa1t;
    int *offs, *perm;
    float *outS, *outA;
  } graphs[2] = {
      {emb_sr, attr_sr, vals_sr, col_sr, Wa11t, offs_sr, perm_sr, out_sr, out_sra},
      {emb_tg, attr_tg, vals_tg, col_tg, Wa12t, offs_tg, perm_tg, out_tg, out_tga},
  };

  for (int g = 0; g < 2; ++g) {
    G& gr = graphs[g];
    // structural branch: 2 GCN layers + l2norm
    cvt_pad_k<<<dim3(DP / 256, MP), 256, 0, stream>>>(gr.emb, N, Dd, B0, DP);
    gemm_bf16_k<<<dim3(MBLK, 8), 256, 0, stream>>>(B0, DP, Ws0t, DP, B1, DP, DP);
    spmm_relu_k<<<dim3(N, 4), 256, 0, stream>>>(gr.offs, gr.perm, gr.col, gr.vals,
                                                B1, DP, B0, DP, nullptr, 0);
    gemm_bf16_k<<<dim3(MBLK, 8), 256, 0, stream>>>(B0, DP, Ws1t, DP, B1, DP, DP);
    spmm_relu_k<<<dim3(N, 4), 256, 0, stream>>>(gr.offs, gr.perm, gr.col, gr.vals,
                                                B1, DP, B0, DP, nullptr, 0);
    l2norm_k<<<dim3(N), 256, 0, stream>>>(B0, DP, gr.outS, Dd);

    // attribute branch: 2 GCN layers, no norm, f32 out on last spmm
    cvt_pad_k<<<dim3(DP / 256, MP), 256, 0, stream>>>(gr.attr, N, Dd, B0, DP);
    gemm_bf16_k<<<dim3(MBLK, 1), 256, 0, stream>>>(B0, DP, gr.Wa1t, DP, B1, DP, DP);
    spmm_relu_k<<<dim3(N, 1), 128, 0, stream>>>(gr.offs, gr.perm, gr.col, gr.vals,
                                                B1, DP, B0, DP, nullptr, 0);
    gemm_bf16_k<<<dim3(MBLK, 1), 256, 0, stream>>>(B0, DP, Wa2t, DAP, B1, DP, DAP);
    spmm_relu_k<<<dim3(N, 1), 128, 0, stream>>>(gr.offs, gr.perm, gr.col, gr.vals,
                                                B1, DP, nullptr, 0, gr.outA, DA);
  }
}

// Round 2
// 919.539 us; speedup vs baseline: 1.7444x; 1.7444x over previous
//
#include <hip/hip_runtime.h>

#define N_NODES 20000
#define D_IN    1000
#define E_EDGES 160000
#define DA      100

#define MP   20096    // 157 * 128 (padded rows)
#define DP   1024     // padded K / structural cols
#define DAP  128      // padded attr cols
#define MBLK 157
#define PEMAX (E_EDGES + 4 * N_NODES)   // padded edge capacity (rows padded to x4)

typedef __bf16 bf16x8 __attribute__((ext_vector_type(8)));
typedef float  f32x4  __attribute__((ext_vector_type(4)));

__device__ __forceinline__ short f2bf(float f) {
  unsigned u = __float_as_uint(f);
  return (short)((u + 0x7FFFu + ((u >> 16) & 1u)) >> 16);   // RNE
}
__device__ __forceinline__ float bf2f(short s) {
  return __uint_as_float(((unsigned)(unsigned short)s) << 16);
}

#define GLDS16(g, l) __builtin_amdgcn_global_load_lds( \
    (const __attribute__((address_space(1))) void*)(g), \
    (__attribute__((address_space(3))) void*)(l), 16, 0, 0)

// ---------------------------------------------------------------- conversions

__global__ void cvt_pad_k(const float* __restrict__ src, int R, int C,
                          short* __restrict__ dst, int Cp) {
  int r = blockIdx.y;
  int c = blockIdx.x * blockDim.x + threadIdx.x;
  float v = (r < R && c < C) ? src[(size_t)r * C + c] : 0.f;
  dst[(size_t)r * Cp + c] = f2bf(v);
}

__global__ void cvt_w_t_k(const float* __restrict__ src, int K, int Nc,
                          short* __restrict__ dst, int Kp) {
  int n = blockIdx.y;
  int k = blockIdx.x * blockDim.x + threadIdx.x;
  if (k >= Kp) return;
  float v = (k < K && n < Nc) ? src[(size_t)k * Nc + n] : 0.f;
  dst[(size_t)n * Kp + k] = f2bf(v);
}

__global__ void zero_int_k(int* p, int n) {
  int i = blockIdx.x * blockDim.x + threadIdx.x;
  if (i < n) p[i] = 0;
}

// ---------------------------------------------------------------- CSR build (padded)

__global__ void hist_k(const int* __restrict__ row, int E, int* __restrict__ deg) {
  int e = blockIdx.x * blockDim.x + threadIdx.x;
  if (e < E) atomicAdd(&deg[row[e]], 1);
}

#define SCAN_T 1024
#define SCAN_C 20
// exclusive scan of round_up(deg,4): poffs[0]=0, poffs[r+1]=sum_{i<=r} pad4(deg[i])
__launch_bounds__(SCAN_T)
__global__ void scan_pad_k(const int* __restrict__ deg, int n, int* __restrict__ poffs) {
  __shared__ int lds[SCAN_T];
  int t = threadIdx.x;
  int base = t * SCAN_C;
  int v[SCAN_C];
  int s = 0;
#pragma unroll
  for (int i = 0; i < SCAN_C; ++i) {
    int idx = base + i;
    int x = (idx < n) ? ((deg[idx] + 3) & ~3) : 0;
    s += x;
    v[i] = s;
  }
  lds[t] = s;
  __syncthreads();
  for (int off = 1; off < SCAN_T; off <<= 1) {
    int add = (t >= off) ? lds[t - off] : 0;
    __syncthreads();
    lds[t] += add;
    __syncthreads();
  }
  int prefix = lds[t] - s;
#pragma unroll
  for (int i = 0; i < SCAN_C; ++i) {
    int idx = base + i;
    if (idx < n) poffs[idx + 1] = v[i] + prefix;
  }
  if (t == 0) poffs[0] = 0;
}

// packed[pos] = {col, bits(val)} at padded CSR position
__global__ void scatter_pack_k(const int* __restrict__ row, const int* __restrict__ col,
                               const float* __restrict__ vals, int E,
                               const int* __restrict__ poffs, int* __restrict__ cursor,
                               int2* __restrict__ packed) {
  int e = blockIdx.x * blockDim.x + threadIdx.x;
  if (e < E) {
    int r = row[e];
    int p = atomicAdd(&cursor[r], 1);
    packed[poffs[r] + p] = make_int2(col[e], __float_as_int(vals[e]));
  }
}

// ---------------------------------------------------------------- GEMM (bf16 MFMA)
// C[M x Nc] = A[M x K] * Bt[Nc x K]^T, bf16 in, f32 accum, bf16 out.
__launch_bounds__(256, 2)
__global__ void gemm_bf16_k(const short* __restrict__ A, int lda,
                            const short* __restrict__ Bt, int ldb,
                            short* __restrict__ C, int ldc, int K) {
  __shared__ short As[128 * 64];
  __shared__ short Bs[128 * 64];

  const int tid  = threadIdx.x;
  const int lane = tid & 63;
  const int wid  = tid >> 6;
  const int wr   = wid >> 1;
  const int wc   = wid & 1;
  const int rowBase = blockIdx.x * 128;
  const int colBase = blockIdx.y * 128;

  const int lrow = lane >> 3;
  const int kofs = (lane & 7) * 8;

  f32x4 acc[4][4];
#pragma unroll
  for (int m = 0; m < 4; ++m)
#pragma unroll
    for (int n = 0; n < 4; ++n)
      acc[m][n] = (f32x4){0.f, 0.f, 0.f, 0.f};

  for (int k0 = 0; k0 < K; k0 += 64) {
#pragma unroll
    for (int c = 0; c < 4; ++c) {
      int chunk = wid * 4 + c;
      int r = chunk * 8 + lrow;
      const short* g = A + (size_t)(rowBase + r) * lda + k0 + kofs;
      GLDS16(g, &As[chunk * 8 * 64]);
    }
#pragma unroll
    for (int c = 0; c < 4; ++c) {
      int chunk = wid * 4 + c;
      int r = chunk * 8 + lrow;
      const short* g = Bt + (size_t)(colBase + r) * ldb + k0 + kofs;
      GLDS16(g, &Bs[chunk * 8 * 64]);
    }
    __syncthreads();

    bf16x8 af[2][4], bfr[2][4];
#pragma unroll
    for (int kk = 0; kk < 2; ++kk) {
#pragma unroll
      for (int i = 0; i < 4; ++i) {
        int ar = wr * 64 + i * 16 + (lane & 15);
        af[kk][i]  = *(const bf16x8*)&As[ar * 64 + kk * 32 + (lane >> 4) * 8];
        int br = wc * 64 + i * 16 + (lane & 15);
        bfr[kk][i] = *(const bf16x8*)&Bs[br * 64 + kk * 32 + (lane >> 4) * 8];
      }
    }
#pragma unroll
    for (int kk = 0; kk < 2; ++kk)
#pragma unroll
      for (int m = 0; m < 4; ++m)
#pragma unroll
        for (int n = 0; n < 4; ++n)
          acc[m][n] = __builtin_amdgcn_mfma_f32_16x16x32_bf16(
              af[kk][m], bfr[kk][n], acc[m][n], 0, 0, 0);
    __syncthreads();
  }

#pragma unroll
  for (int m = 0; m < 4; ++m) {
#pragma unroll
    for (int n = 0; n < 4; ++n) {
      int row0 = rowBase + wr * 64 + m * 16 + (lane >> 4) * 4;
      int col  = colBase + wc * 64 + n * 16 + (lane & 15);
#pragma unroll
      for (int reg = 0; reg < 4; ++reg)
        C[(size_t)(row0 + reg) * ldc + col] = f2bf(acc[m][n][reg]);
    }
  }
}

// ---------------------------------------------------------------- SpMM + ReLU (v2)
// Padded CSR: row r owns packed[poffs[r] .. poffs[r+1]) with length % 4 == 0;
// pad entries are {col=0, val=0} (contribute nothing).
// Each thread accumulates VEC contiguous columns; 4 independent gathers/iter.
template<int TPB, int VEC>
__launch_bounds__(TPB)
__global__ void spmm_relu_v2(const int* __restrict__ poffs,
                             const int2* __restrict__ packed,
                             const short* __restrict__ S, int ldS,
                             short* __restrict__ outB, int ldB,
                             float* __restrict__ outF, int outCols) {
  typedef short sv __attribute__((ext_vector_type(VEC)));
  int r  = blockIdx.x;
  int c0 = (blockIdx.y * TPB + threadIdx.x) * VEC;
  int e0 = poffs[r], e1 = poffs[r + 1];

  float acc[VEC];
#pragma unroll
  for (int j = 0; j < VEC; ++j) acc[j] = 0.f;

  for (int i = e0; i < e1; i += 4) {
    const int4* p4 = (const int4*)&packed[i];   // 32B aligned (i % 4 == 0)
    int4 a = p4[0];
    int4 b = p4[1];
    sv s0 = *(const sv*)&S[(size_t)a.x * ldS + c0];
    sv s1 = *(const sv*)&S[(size_t)a.z * ldS + c0];
    sv s2 = *(const sv*)&S[(size_t)b.x * ldS + c0];
    sv s3 = *(const sv*)&S[(size_t)b.z * ldS + c0];
    float v0 = __int_as_float(a.y);
    float v1 = __int_as_float(a.w);
    float v2 = __int_as_float(b.y);
    float v3 = __int_as_float(b.w);
#pragma unroll
    for (int j = 0; j < VEC; ++j) {
      acc[j] += v0 * bf2f(s0[j]);
      acc[j] += v1 * bf2f(s1[j]);
      acc[j] += v2 * bf2f(s2[j]);
      acc[j] += v3 * bf2f(s3[j]);
    }
  }

  if (outB) {
    sv o;
#pragma unroll
    for (int j = 0; j < VEC; ++j) o[j] = f2bf(fmaxf(acc[j], 0.f));
    *(sv*)&outB[(size_t)r * ldB + c0] = o;
  } else {
#pragma unroll
    for (int j = 0; j < VEC; ++j)
      if (c0 + j < outCols)
        outF[(size_t)r * outCols + c0 + j] = fmaxf(acc[j], 0.f);
  }
}

// ---------------------------------------------------------------- row l2 norm
__global__ void l2norm_k(const short* __restrict__ H, int ldH,
                         float* __restrict__ out, int cols) {
  __shared__ float red[4];
  int r = blockIdx.x;
  int t = threadIdx.x;
  float s = 0.f;
  for (int c = t; c < ldH; c += 256) {
    float v = bf2f(H[(size_t)r * ldH + c]);
    s += v * v;
  }
  for (int off = 32; off >= 1; off >>= 1) s += __shfl_down(s, off, 64);
  if ((t & 63) == 0) red[t >> 6] = s;
  __syncthreads();
  float tot = red[0] + red[1] + red[2] + red[3];
  float inv = 1.f / fmaxf(sqrtf(tot), 1e-12f);
  for (int c = t; c < cols; c += 256)
    out[(size_t)r * cols + c] = bf2f(H[(size_t)r * ldH + c]) * inv;
}

// ---------------------------------------------------------------- launch

extern "C" void kernel_launch(void* const* d_in, const int* in_sizes, int n_in,
                              void* d_out, int out_size, void* d_ws, size_t ws_size,
                              hipStream_t stream) {
  const float* emb_sr  = (const float*)d_in[0];
  const float* emb_tg  = (const float*)d_in[1];
  const float* attr_sr = (const float*)d_in[2];
  const float* attr_tg = (const float*)d_in[3];
  const int*   row_sr  = (const int*)d_in[4];
  const int*   col_sr  = (const int*)d_in[5];
  const float* vals_sr = (const float*)d_in[6];
  const int*   row_tg  = (const int*)d_in[7];
  const int*   col_tg  = (const int*)d_in[8];
  const float* vals_tg = (const float*)d_in[9];
  const float* W_s0    = (const float*)d_in[10];
  const float* W_s1    = (const float*)d_in[11];
  const float* W_a11   = (const float*)d_in[12];
  const float* W_a12   = (const float*)d_in[13];
  const float* W_a2    = (const float*)d_in[14];

  const int N = N_NODES, Dd = D_IN, E = E_EDGES;

  char* ws = (char*)d_ws;
  size_t off = 0;
  auto alloc = [&](size_t bytes) -> void* {
    void* p = ws + off;
    off += (bytes + 255) & ~(size_t)255;
    return p;
  };
  short* B0     = (short*)alloc((size_t)MP * DP * 2);
  short* B1     = (short*)alloc((size_t)MP * DP * 2);
  short* Ws0t   = (short*)alloc((size_t)DP * DP * 2);
  short* Ws1t   = (short*)alloc((size_t)DP * DP * 2);
  short* Wa11t  = (short*)alloc((size_t)DAP * DP * 2);
  short* Wa12t  = (short*)alloc((size_t)DAP * DP * 2);
  short* Wa2t   = (short*)alloc((size_t)DAP * DAP * 2);
  int*  deg_sr  = (int*)alloc((size_t)N * 4);
  int*  deg_tg  = (int*)alloc((size_t)N * 4);
  int*  cur_sr  = (int*)alloc((size_t)N * 4);
  int*  cur_tg  = (int*)alloc((size_t)N * 4);
  int*  poffs_sr = (int*)alloc((size_t)(N + 1) * 4);
  int*  poffs_tg = (int*)alloc((size_t)(N + 1) * 4);
  int2* pack_sr = (int2*)alloc((size_t)PEMAX * 8);
  int2* pack_tg = (int2*)alloc((size_t)PEMAX * 8);
  if (off > ws_size) return;

  float* out_sr  = (float*)d_out;
  float* out_tg  = out_sr + (size_t)N * Dd;
  float* out_sra = out_tg + (size_t)N * Dd;
  float* out_tga = out_sra + (size_t)N * DA;

  // ---- padded-CSR build for both graphs
  zero_int_k<<<dim3((N * 2 + 255) / 256), 256, 0, stream>>>(deg_sr, N);
  zero_int_k<<<dim3((N + 255) / 256), 256, 0, stream>>>(deg_tg, N);
  zero_int_k<<<dim3((N + 255) / 256), 256, 0, stream>>>(cur_sr, N);
  zero_int_k<<<dim3((N + 255) / 256), 256, 0, stream>>>(cur_tg, N);
  zero_int_k<<<dim3((PEMAX * 2 + 255) / 256), 256, 0, stream>>>((int*)pack_sr, PEMAX * 2);
  zero_int_k<<<dim3((PEMAX * 2 + 255) / 256), 256, 0, stream>>>((int*)pack_tg, PEMAX * 2);
  hist_k<<<dim3((E + 255) / 256), 256, 0, stream>>>(row_sr, E, deg_sr);
  hist_k<<<dim3((E + 255) / 256), 256, 0, stream>>>(row_tg, E, deg_tg);
  scan_pad_k<<<1, SCAN_T, 0, stream>>>(deg_sr, N, poffs_sr);
  scan_pad_k<<<1, SCAN_T, 0, stream>>>(deg_tg, N, poffs_tg);
  scatter_pack_k<<<dim3((E + 255) / 256), 256, 0, stream>>>(row_sr, col_sr, vals_sr, E,
                                                            poffs_sr, cur_sr, pack_sr);
  scatter_pack_k<<<dim3((E + 255) / 256), 256, 0, stream>>>(row_tg, col_tg, vals_tg, E,
                                                            poffs_tg, cur_tg, pack_tg);

  // ---- weight conversions (transposed + padded)
  cvt_w_t_k<<<dim3(DP / 256, DP), 256, 0, stream>>>(W_s0, Dd, Dd, Ws0t, DP);
  cvt_w_t_k<<<dim3(DP / 256, DP), 256, 0, stream>>>(W_s1, Dd, Dd, Ws1t, DP);
  cvt_w_t_k<<<dim3(DP / 256, DAP), 256, 0, stream>>>(W_a11, Dd, DA, Wa11t, DP);
  cvt_w_t_k<<<dim3(DP / 256, DAP), 256, 0, stream>>>(W_a12, Dd, DA, Wa12t, DP);
  cvt_w_t_k<<<dim3(1, DAP), 256, 0, stream>>>(W_a2, DA, DA, Wa2t, DAP);

  // ---- per-graph pipelines
  struct G {
    const float *emb, *attr;
    const short *Wa1t;
    int *poffs;
    int2 *pack;
    float *outS, *outA;
  } graphs[2] = {
      {emb_sr, attr_sr, Wa11t, poffs_sr, pack_sr, out_sr, out_sra},
      {emb_tg, attr_tg, Wa12t, poffs_tg, pack_tg, out_tg, out_tga},
  };

  for (int g = 0; g < 2; ++g) {
    G& gr = graphs[g];
    // structural branch
    cvt_pad_k<<<dim3(DP / 256, MP), 256, 0, stream>>>(gr.emb, N, Dd, B0, DP);
    gemm_bf16_k<<<dim3(MBLK, 8), 256, 0, stream>>>(B0, DP, Ws0t, DP, B1, DP, DP);
    spmm_relu_v2<128, 8><<<dim3(N, 1), 128, 0, stream>>>(gr.poffs, gr.pack, B1, DP,
                                                         B0, DP, nullptr, 0);
    gemm_bf16_k<<<dim3(MBLK, 8), 256, 0, stream>>>(B0, DP, Ws1t, DP, B1, DP, DP);
    spmm_relu_v2<128, 8><<<dim3(N, 1), 128, 0, stream>>>(gr.poffs, gr.pack, B1, DP,
                                                         B0, DP, nullptr, 0);
    l2norm_k<<<dim3(N), 256, 0, stream>>>(B0, DP, gr.outS, Dd);

    // attribute branch (128 padded cols)
    cvt_pad_k<<<dim3(DP / 256, MP), 256, 0, stream>>>(gr.attr, N, Dd, B0, DP);
    gemm_bf16_k<<<dim3(MBLK, 1), 256, 0, stream>>>(B0, DP, gr.Wa1t, DP, B1, DP, DP);
    spmm_relu_v2<64, 2><<<dim3(N, 1), 64, 0, stream>>>(gr.poffs, gr.pack, B1, DP,
                                                       B0, DP, nullptr, 0);
    gemm_bf16_k<<<dim3(MBLK, 1), 256, 0, stream>>>(B0, DP, Wa2t, DAP, B1, DP, DAP);
    spmm_relu_v2<64, 2><<<dim3(N, 1), 64, 0, stream>>>(gr.poffs, gr.pack, B1, DP,
                                                       nullptr, 0, gr.outA, DA);
  }
}

// Round 3
// 746.334 us; speedup vs baseline: 2.1492x; 1.2321x over previous
//
#include <hip/hip_runtime.h>

#define N_NODES 20000
#define D_IN    1000
#define E_EDGES 160000
#define DA      100

#define MP   20096    // 157 * 128 (padded rows)
#define DP   1024     // padded K / structural cols
#define DAP  128      // padded attr cols
#define MBLK 157
#define PEMAX (E_EDGES + 4 * N_NODES)   // padded edge capacity (rows padded to x4)

typedef __bf16 bf16x8 __attribute__((ext_vector_type(8)));
typedef float  f32x4  __attribute__((ext_vector_type(4)));

__device__ __forceinline__ short f2bf(float f) {
  unsigned u = __float_as_uint(f);
  return (short)((u + 0x7FFFu + ((u >> 16) & 1u)) >> 16);   // RNE
}
__device__ __forceinline__ float bf2f(short s) {
  return __uint_as_float(((unsigned)(unsigned short)s) << 16);
}

#define GLDS16(g, l) __builtin_amdgcn_global_load_lds( \
    (const __attribute__((address_space(1))) void*)(g), \
    (__attribute__((address_space(3))) void*)(l), 16, 0, 0)

// ---------------------------------------------------------------- conversions

// batched (z=2) f32->bf16 pad, float4 loads. grid: (1, MP, 2), 256 thr (1024 cols)
__global__ void cvt_pad2_k(const float* __restrict__ s0, const float* __restrict__ s1,
                           int R, int C,
                           short* __restrict__ d0, short* __restrict__ d1, int Cp) {
  const float* src = blockIdx.z ? s1 : s0;
  short* dst = blockIdx.z ? d1 : d0;
  int r = blockIdx.y;
  int c0 = threadIdx.x * 4;
  short4 o = {0, 0, 0, 0};
  if (r < R) {
    if (c0 + 3 < C) {
      float4 v = *(const float4*)&src[(size_t)r * C + c0];
      o.x = f2bf(v.x); o.y = f2bf(v.y); o.z = f2bf(v.z); o.w = f2bf(v.w);
    } else {
#pragma unroll
      for (int j = 0; j < 4; ++j) {
        float v = (c0 + j < C) ? src[(size_t)r * C + c0 + j] : 0.f;
        ((short*)&o)[j] = f2bf(v);
      }
    }
  }
  *(short4*)&dst[(size_t)r * Cp + c0] = o;
}

// batched (z=2) W transpose+pad: dst[n*Kp+k] = bf16(src[k*Nc+n]). grid ((Kp+255)/256, Np, 2)
__global__ void cvt_w_t2_k(const float* __restrict__ s0, const float* __restrict__ s1,
                           int K, int Nc,
                           short* __restrict__ d0, short* __restrict__ d1, int Kp) {
  const float* src = blockIdx.z ? s1 : s0;
  short* dst = blockIdx.z ? d1 : d0;
  int n = blockIdx.y;
  int k = blockIdx.x * blockDim.x + threadIdx.x;
  if (k >= Kp) return;
  float v = (k < K && n < Nc) ? src[(size_t)k * Nc + n] : 0.f;
  dst[(size_t)n * Kp + k] = f2bf(v);
}

__global__ void zero_int_k(int* p, int n) {
  int i = blockIdx.x * blockDim.x + threadIdx.x;
  if (i < n) p[i] = 0;
}

// ---------------------------------------------------------------- CSR build (padded, both graphs)

__global__ void hist2_k(const int* __restrict__ row0, const int* __restrict__ row1, int E,
                        int* __restrict__ deg0, int* __restrict__ deg1) {
  int e = blockIdx.x * blockDim.x + threadIdx.x;
  if (e < E) atomicAdd(&deg0[row0[e]], 1);
  else if (e < 2 * E) atomicAdd(&deg1[row1[e - E]], 1);
}

#define SCAN_T 1024
#define SCAN_C 20
// exclusive scan of round_up(deg,4); grid 2 blocks (one per graph)
__launch_bounds__(SCAN_T)
__global__ void scan_pad2_k(const int* __restrict__ dg0, const int* __restrict__ dg1, int n,
                            int* __restrict__ p0, int* __restrict__ p1) {
  const int* deg = blockIdx.x ? dg1 : dg0;
  int* poffs = blockIdx.x ? p1 : p0;
  __shared__ int lds[SCAN_T];
  int t = threadIdx.x;
  int base = t * SCAN_C;
  int v[SCAN_C];
  int s = 0;
#pragma unroll
  for (int i = 0; i < SCAN_C; ++i) {
    int idx = base + i;
    int x = (idx < n) ? ((deg[idx] + 3) & ~3) : 0;
    s += x;
    v[i] = s;
  }
  lds[t] = s;
  __syncthreads();
  for (int off = 1; off < SCAN_T; off <<= 1) {
    int add = (t >= off) ? lds[t - off] : 0;
    __syncthreads();
    lds[t] += add;
    __syncthreads();
  }
  int prefix = lds[t] - s;
#pragma unroll
  for (int i = 0; i < SCAN_C; ++i) {
    int idx = base + i;
    if (idx < n) poffs[idx + 1] = v[i] + prefix;
  }
  if (t == 0) poffs[0] = 0;
}

__global__ void scatter_pack2_k(const int* __restrict__ row0, const int* __restrict__ col0,
                                const float* __restrict__ val0,
                                const int* __restrict__ row1, const int* __restrict__ col1,
                                const float* __restrict__ val1, int E,
                                const int* __restrict__ po0, const int* __restrict__ po1,
                                int* __restrict__ cur0, int* __restrict__ cur1,
                                int2* __restrict__ pk0, int2* __restrict__ pk1) {
  int e = blockIdx.x * blockDim.x + threadIdx.x;
  if (e < E) {
    int r = row0[e];
    int p = atomicAdd(&cur0[r], 1);
    pk0[po0[r] + p] = make_int2(col0[e], __float_as_int(val0[e]));
  } else if (e < 2 * E) {
    int ee = e - E;
    int r = row1[ee];
    int p = atomicAdd(&cur1[r], 1);
    pk1[po1[r] + p] = make_int2(col1[ee], __float_as_int(val1[ee]));
  }
}

// ---------------------------------------------------------------- GEMM (bf16 MFMA, z=2 batched)
// C[M x Nc] = A[M x K] * Bt[Nc x K]^T, bf16 in, f32 accum, bf16 out.
// grid: (Nc/128, MBLK, 2) -- col-block fastest so XCD k keeps B-panel k L2-resident.
__launch_bounds__(256, 2)
__global__ void gemm_bf16_k(const short* __restrict__ A0, const short* __restrict__ A1, int lda,
                            const short* __restrict__ Bt0, const short* __restrict__ Bt1, int ldb,
                            short* __restrict__ C0, short* __restrict__ C1, int ldc, int K) {
  __shared__ short As[128 * 64];
  __shared__ short Bs[128 * 64];

  const short* A  = blockIdx.z ? A1 : A0;
  const short* Bt = blockIdx.z ? Bt1 : Bt0;
  short* C        = blockIdx.z ? C1 : C0;

  const int tid  = threadIdx.x;
  const int lane = tid & 63;
  const int wid  = tid >> 6;
  const int wr   = wid >> 1;
  const int wc   = wid & 1;
  const int rowBase = blockIdx.y * 128;
  const int colBase = blockIdx.x * 128;

  const int lrow = lane >> 3;
  const int kofs = (lane & 7) * 8;

  f32x4 acc[4][4];
#pragma unroll
  for (int m = 0; m < 4; ++m)
#pragma unroll
    for (int n = 0; n < 4; ++n)
      acc[m][n] = (f32x4){0.f, 0.f, 0.f, 0.f};

  for (int k0 = 0; k0 < K; k0 += 64) {
#pragma unroll
    for (int c = 0; c < 4; ++c) {
      int chunk = wid * 4 + c;
      int r = chunk * 8 + lrow;
      const short* g = A + (size_t)(rowBase + r) * lda + k0 + kofs;
      GLDS16(g, &As[chunk * 8 * 64]);
    }
#pragma unroll
    for (int c = 0; c < 4; ++c) {
      int chunk = wid * 4 + c;
      int r = chunk * 8 + lrow;
      const short* g = Bt + (size_t)(colBase + r) * ldb + k0 + kofs;
      GLDS16(g, &Bs[chunk * 8 * 64]);
    }
    __syncthreads();

    bf16x8 af[2][4], bfr[2][4];
#pragma unroll
    for (int kk = 0; kk < 2; ++kk) {
#pragma unroll
      for (int i = 0; i < 4; ++i) {
        int ar = wr * 64 + i * 16 + (lane & 15);
        af[kk][i]  = *(const bf16x8*)&As[ar * 64 + kk * 32 + (lane >> 4) * 8];
        int br = wc * 64 + i * 16 + (lane & 15);
        bfr[kk][i] = *(const bf16x8*)&Bs[br * 64 + kk * 32 + (lane >> 4) * 8];
      }
    }
#pragma unroll
    for (int kk = 0; kk < 2; ++kk)
#pragma unroll
      for (int m = 0; m < 4; ++m)
#pragma unroll
        for (int n = 0; n < 4; ++n)
          acc[m][n] = __builtin_amdgcn_mfma_f32_16x16x32_bf16(
              af[kk][m], bfr[kk][n], acc[m][n], 0, 0, 0);
    __syncthreads();
  }

#pragma unroll
  for (int m = 0; m < 4; ++m) {
#pragma unroll
    for (int n = 0; n < 4; ++n) {
      int row0 = rowBase + wr * 64 + m * 16 + (lane >> 4) * 4;
      int col  = colBase + wc * 64 + n * 16 + (lane & 15);
#pragma unroll
      for (int reg = 0; reg < 4; ++reg)
        C[(size_t)(row0 + reg) * ldc + col] = f2bf(acc[m][n][reg]);
    }
  }
}

// ---------------------------------------------------------------- SpMM + ReLU (z=2, RPB rows/block)
template<int TPB, int VEC, int RPB>
__launch_bounds__(TPB)
__global__ void spmm_relu_v3(const int* __restrict__ po0, const int* __restrict__ po1,
                             const int2* __restrict__ pk0, const int2* __restrict__ pk1,
                             const short* __restrict__ S0, const short* __restrict__ S1, int ldS,
                             short* __restrict__ oB0, short* __restrict__ oB1, int ldB,
                             float* __restrict__ oF0, float* __restrict__ oF1, int outCols) {
  typedef short sv __attribute__((ext_vector_type(VEC)));
  const int* poffs    = blockIdx.z ? po1 : po0;
  const int2* packed  = blockIdx.z ? pk1 : pk0;
  const short* S      = blockIdx.z ? S1 : S0;
  short* outB         = blockIdx.z ? oB1 : oB0;
  float* outF         = blockIdx.z ? oF1 : oF0;
  int c0 = threadIdx.x * VEC;

  int rEnd = blockIdx.x * RPB + RPB;
  for (int r = blockIdx.x * RPB; r < rEnd; ++r) {
    int e0 = poffs[r], e1 = poffs[r + 1];
    float acc[VEC];
#pragma unroll
    for (int j = 0; j < VEC; ++j) acc[j] = 0.f;

    for (int i = e0; i < e1; i += 4) {
      const int4* p4 = (const int4*)&packed[i];   // 32B aligned (i % 4 == 0)
      int4 a = p4[0];
      int4 b = p4[1];
      sv s0 = *(const sv*)&S[(size_t)a.x * ldS + c0];
      sv s1 = *(const sv*)&S[(size_t)a.z * ldS + c0];
      sv s2 = *(const sv*)&S[(size_t)b.x * ldS + c0];
      sv s3 = *(const sv*)&S[(size_t)b.z * ldS + c0];
      float v0 = __int_as_float(a.y);
      float v1 = __int_as_float(a.w);
      float v2 = __int_as_float(b.y);
      float v3 = __int_as_float(b.w);
#pragma unroll
      for (int j = 0; j < VEC; ++j) {
        acc[j] += v0 * bf2f(s0[j]);
        acc[j] += v1 * bf2f(s1[j]);
        acc[j] += v2 * bf2f(s2[j]);
        acc[j] += v3 * bf2f(s3[j]);
      }
    }

    if (outB) {
      sv o;
#pragma unroll
      for (int j = 0; j < VEC; ++j) o[j] = f2bf(fmaxf(acc[j], 0.f));
      *(sv*)&outB[(size_t)r * ldB + c0] = o;
    } else {
#pragma unroll
      for (int j = 0; j < VEC; ++j)
        if (c0 + j < outCols)
          outF[(size_t)r * outCols + c0 + j] = fmaxf(acc[j], 0.f);
    }
  }
}

// ---------------------------------------------------------------- row l2 norm (z=2)
__global__ void l2norm2_k(const short* __restrict__ H0, const short* __restrict__ H1, int ldH,
                          float* __restrict__ o0, float* __restrict__ o1, int cols) {
  const short* H = blockIdx.y ? H1 : H0;
  float* out = blockIdx.y ? o1 : o0;
  __shared__ float red[4];
  int r = blockIdx.x;
  int t = threadIdx.x;
  float s = 0.f;
  for (int c = t; c < ldH; c += 256) {
    float v = bf2f(H[(size_t)r * ldH + c]);
    s += v * v;
  }
  for (int off = 32; off >= 1; off >>= 1) s += __shfl_down(s, off, 64);
  if ((t & 63) == 0) red[t >> 6] = s;
  __syncthreads();
  float tot = red[0] + red[1] + red[2] + red[3];
  float inv = 1.f / fmaxf(sqrtf(tot), 1e-12f);
  for (int c = t; c < cols; c += 256)
    out[(size_t)r * cols + c] = bf2f(H[(size_t)r * ldH + c]) * inv;
}

// ---------------------------------------------------------------- launch

extern "C" void kernel_launch(void* const* d_in, const int* in_sizes, int n_in,
                              void* d_out, int out_size, void* d_ws, size_t ws_size,
                              hipStream_t stream) {
  const float* emb_sr  = (const float*)d_in[0];
  const float* emb_tg  = (const float*)d_in[1];
  const float* attr_sr = (const float*)d_in[2];
  const float* attr_tg = (const float*)d_in[3];
  const int*   row_sr  = (const int*)d_in[4];
  const int*   col_sr  = (const int*)d_in[5];
  const float* vals_sr = (const float*)d_in[6];
  const int*   row_tg  = (const int*)d_in[7];
  const int*   col_tg  = (const int*)d_in[8];
  const float* vals_tg = (const float*)d_in[9];
  const float* W_s0    = (const float*)d_in[10];
  const float* W_s1    = (const float*)d_in[11];
  const float* W_a11   = (const float*)d_in[12];
  const float* W_a12   = (const float*)d_in[13];
  const float* W_a2    = (const float*)d_in[14];

  const int N = N_NODES, Dd = D_IN, E = E_EDGES;

  char* ws = (char*)d_ws;
  size_t off = 0;
  auto alloc = [&](size_t bytes) -> void* {
    void* p = ws + off;
    off += (bytes + 255) & ~(size_t)255;
    return p;
  };
  // big ping-pong buffers, per graph
  short* X0 = (short*)alloc((size_t)MP * DP * 2);
  short* X1 = (short*)alloc((size_t)MP * DP * 2);
  short* T0 = (short*)alloc((size_t)MP * DP * 2);
  short* T1 = (short*)alloc((size_t)MP * DP * 2);
  // weights
  short* Ws0t  = (short*)alloc((size_t)DP * DP * 2);
  short* Ws1t  = (short*)alloc((size_t)DP * DP * 2);
  short* Wa11t = (short*)alloc((size_t)DAP * DP * 2);
  short* Wa12t = (short*)alloc((size_t)DAP * DP * 2);
  short* Wa2t  = (short*)alloc((size_t)DAP * DAP * 2);
  // CSR: contiguous zero region [deg0|cur0|deg1|cur1|pack0|pack1]
  int*  ibuf    = (int*)alloc((size_t)4 * N * 4);
  int2* pack_sr = (int2*)alloc((size_t)PEMAX * 8);
  int2* pack_tg = (int2*)alloc((size_t)PEMAX * 8);
  int*  poffs_sr = (int*)alloc((size_t)(N + 1) * 4);
  int*  poffs_tg = (int*)alloc((size_t)(N + 1) * 4);
  if (off > ws_size) return;

  int* deg_sr = ibuf;
  int* cur_sr = ibuf + N;
  int* deg_tg = ibuf + 2 * N;
  int* cur_tg = ibuf + 3 * N;
  const int ZERO_N = 4 * N + 2 * (PEMAX * 2);   // contiguous ints incl. both packs

  float* out_sr  = (float*)d_out;
  float* out_tg  = out_sr + (size_t)N * Dd;
  float* out_sra = out_tg + (size_t)N * Dd;
  float* out_tga = out_sra + (size_t)N * DA;

  // ---- padded-CSR build, both graphs batched
  zero_int_k<<<dim3((ZERO_N + 255) / 256), 256, 0, stream>>>(ibuf, ZERO_N);
  hist2_k<<<dim3((2 * E + 255) / 256), 256, 0, stream>>>(row_sr, row_tg, E, deg_sr, deg_tg);
  scan_pad2_k<<<2, SCAN_T, 0, stream>>>(deg_sr, deg_tg, N, poffs_sr, poffs_tg);
  scatter_pack2_k<<<dim3((2 * E + 255) / 256), 256, 0, stream>>>(
      row_sr, col_sr, vals_sr, row_tg, col_tg, vals_tg, E,
      poffs_sr, poffs_tg, cur_sr, cur_tg, pack_sr, pack_tg);

  // ---- weight conversions (transposed + padded), batched
  cvt_w_t2_k<<<dim3(DP / 256, DP, 2), 256, 0, stream>>>(W_s0, W_s1, Dd, Dd, Ws0t, Ws1t, DP);
  cvt_w_t2_k<<<dim3(DP / 256, DAP, 2), 256, 0, stream>>>(W_a11, W_a12, Dd, DA, Wa11t, Wa12t, DP);
  cvt_w_t2_k<<<dim3(1, DAP, 1), 256, 0, stream>>>(W_a2, W_a2, DA, DA, Wa2t, Wa2t, DAP);

  // ---- structural branch (both graphs in z)
  cvt_pad2_k<<<dim3(1, MP, 2), 256, 0, stream>>>(emb_sr, emb_tg, N, Dd, X0, X1, DP);
  gemm_bf16_k<<<dim3(8, MBLK, 2), 256, 0, stream>>>(X0, X1, DP, Ws0t, Ws0t, DP, T0, T1, DP, DP);
  spmm_relu_v3<128, 8, 4><<<dim3(N / 4, 1, 2), 128, 0, stream>>>(
      poffs_sr, poffs_tg, pack_sr, pack_tg, T0, T1, DP, X0, X1, DP, nullptr, nullptr, 0);
  gemm_bf16_k<<<dim3(8, MBLK, 2), 256, 0, stream>>>(X0, X1, DP, Ws1t, Ws1t, DP, T0, T1, DP, DP);
  spmm_relu_v3<128, 8, 4><<<dim3(N / 4, 1, 2), 128, 0, stream>>>(
      poffs_sr, poffs_tg, pack_sr, pack_tg, T0, T1, DP, X0, X1, DP, nullptr, nullptr, 0);
  l2norm2_k<<<dim3(N, 2), 256, 0, stream>>>(X0, X1, DP, out_sr, out_tg, Dd);

  // ---- attribute branch (both graphs in z)
  cvt_pad2_k<<<dim3(1, MP, 2), 256, 0, stream>>>(attr_sr, attr_tg, N, Dd, X0, X1, DP);
  gemm_bf16_k<<<dim3(1, MBLK, 2), 256, 0, stream>>>(X0, X1, DP, Wa11t, Wa12t, DP, T0, T1, DP, DP);
  spmm_relu_v3<64, 2, 4><<<dim3(N / 4, 1, 2), 64, 0, stream>>>(
      poffs_sr, poffs_tg, pack_sr, pack_tg, T0, T1, DP, X0, X1, DP, nullptr, nullptr, 0);
  gemm_bf16_k<<<dim3(1, MBLK, 2), 256, 0, stream>>>(X0, X1, DP, Wa2t, Wa2t, DAP, T0, T1, DP, DAP);
  spmm_relu_v3<64, 2, 4><<<dim3(N / 4, 1, 2), 64, 0, stream>>>(
      poffs_sr, poffs_tg, pack_sr, pack_tg, T0, T1, DP, nullptr, nullptr, 0, out_sra, out_tga, DA);
}

// Round 4
// 721.298 us; speedup vs baseline: 2.2238x; 1.0347x over previous
//
#include <hip/hip_runtime.h>

#define N_NODES 20000
#define D_IN    1000
#define E_EDGES 160000
#define DA      100

#define MP   20096    // 157 * 128 (padded rows)
#define DP   1024     // padded K / structural cols
#define DAP  128      // padded attr cols
#define MBLK 157
#define PEMAX (E_EDGES + 4 * N_NODES)   // padded edge capacity (rows padded to x4)

typedef __bf16 bf16x8 __attribute__((ext_vector_type(8)));
typedef float  f32x4  __attribute__((ext_vector_type(4)));

__device__ __forceinline__ short f2bf(float f) {
  unsigned u = __float_as_uint(f);
  return (short)((u + 0x7FFFu + ((u >> 16) & 1u)) >> 16);   // RNE
}
__device__ __forceinline__ float bf2f(short s) {
  return __uint_as_float(((unsigned)(unsigned short)s) << 16);
}

#define GLDS16(g, l) __builtin_amdgcn_global_load_lds( \
    (const __attribute__((address_space(1))) void*)(g), \
    (__attribute__((address_space(3))) void*)(l), 16, 0, 0)

// ---------------------------------------------------------------- conversions

// batched (z=2) f32->bf16 pad, float4 loads. grid: (1, MP, 2), 256 thr (1024 cols)
__global__ void cvt_pad2_k(const float* __restrict__ s0, const float* __restrict__ s1,
                           int R, int C,
                           short* __restrict__ d0, short* __restrict__ d1, int Cp) {
  const float* src = blockIdx.z ? s1 : s0;
  short* dst = blockIdx.z ? d1 : d0;
  int r = blockIdx.y;
  int c0 = threadIdx.x * 4;
  short4 o = {0, 0, 0, 0};
  if (r < R) {
    if (c0 + 3 < C) {
      float4 v = *(const float4*)&src[(size_t)r * C + c0];
      o.x = f2bf(v.x); o.y = f2bf(v.y); o.z = f2bf(v.z); o.w = f2bf(v.w);
    } else {
#pragma unroll
      for (int j = 0; j < 4; ++j) {
        float v = (c0 + j < C) ? src[(size_t)r * C + c0 + j] : 0.f;
        ((short*)&o)[j] = f2bf(v);
      }
    }
  }
  *(short4*)&dst[(size_t)r * Cp + c0] = o;
}

// batched (z=2) W transpose+pad: dst[n*Kp+k] = bf16(src[k*Nc+n]). grid ((Kp+255)/256, Np, 2)
__global__ void cvt_w_t2_k(const float* __restrict__ s0, const float* __restrict__ s1,
                           int K, int Nc,
                           short* __restrict__ d0, short* __restrict__ d1, int Kp) {
  const float* src = blockIdx.z ? s1 : s0;
  short* dst = blockIdx.z ? d1 : d0;
  int n = blockIdx.y;
  int k = blockIdx.x * blockDim.x + threadIdx.x;
  if (k >= Kp) return;
  float v = (k < K && n < Nc) ? src[(size_t)k * Nc + n] : 0.f;
  dst[(size_t)n * Kp + k] = f2bf(v);
}

__global__ void zero_int_k(int* p, int n) {
  int i = blockIdx.x * blockDim.x + threadIdx.x;
  if (i < n) p[i] = 0;
}

// ---------------------------------------------------------------- CSR build (padded, both graphs)

__global__ void hist2_k(const int* __restrict__ row0, const int* __restrict__ row1, int E,
                        int* __restrict__ deg0, int* __restrict__ deg1) {
  int e = blockIdx.x * blockDim.x + threadIdx.x;
  if (e < E) atomicAdd(&deg0[row0[e]], 1);
  else if (e < 2 * E) atomicAdd(&deg1[row1[e - E]], 1);
}

#define SCAN_T 1024
#define SCAN_C 20
// exclusive scan of round_up(deg,4); grid 2 blocks (one per graph)
__launch_bounds__(SCAN_T)
__global__ void scan_pad2_k(const int* __restrict__ dg0, const int* __restrict__ dg1, int n,
                            int* __restrict__ p0, int* __restrict__ p1) {
  const int* deg = blockIdx.x ? dg1 : dg0;
  int* poffs = blockIdx.x ? p1 : p0;
  __shared__ int lds[SCAN_T];
  int t = threadIdx.x;
  int base = t * SCAN_C;
  int v[SCAN_C];
  int s = 0;
#pragma unroll
  for (int i = 0; i < SCAN_C; ++i) {
    int idx = base + i;
    int x = (idx < n) ? ((deg[idx] + 3) & ~3) : 0;
    s += x;
    v[i] = s;
  }
  lds[t] = s;
  __syncthreads();
  for (int off = 1; off < SCAN_T; off <<= 1) {
    int add = (t >= off) ? lds[t - off] : 0;
    __syncthreads();
    lds[t] += add;
    __syncthreads();
  }
  int prefix = lds[t] - s;
#pragma unroll
  for (int i = 0; i < SCAN_C; ++i) {
    int idx = base + i;
    if (idx < n) poffs[idx + 1] = v[i] + prefix;
  }
  if (t == 0) poffs[0] = 0;
}

__global__ void scatter_pack2_k(const int* __restrict__ row0, const int* __restrict__ col0,
                                const float* __restrict__ val0,
                                const int* __restrict__ row1, const int* __restrict__ col1,
                                const float* __restrict__ val1, int E,
                                const int* __restrict__ po0, const int* __restrict__ po1,
                                int* __restrict__ cur0, int* __restrict__ cur1,
                                int2* __restrict__ pk0, int2* __restrict__ pk1) {
  int e = blockIdx.x * blockDim.x + threadIdx.x;
  if (e < E) {
    int r = row0[e];
    int p = atomicAdd(&cur0[r], 1);
    pk0[po0[r] + p] = make_int2(col0[e], __float_as_int(val0[e]));
  } else if (e < 2 * E) {
    int ee = e - E;
    int r = row1[ee];
    int p = atomicAdd(&cur1[r], 1);
    pk1[po1[r] + p] = make_int2(col1[ee], __float_as_int(val1[ee]));
  }
}

// ---------------------------------------------------------------- GEMM (bf16 MFMA, z=2 batched)
// C[M x Nc] = A[M x K] * Bt[Nc x K]^T, bf16 in, f32 accum, bf16 out.
// 1-D launch, XCD-aware bijective remap (m204): each XCD gets a contiguous
// work chunk (cols fastest) so its ~64 concurrent blocks share 8 A row-panels
// (2 MB) + 8 B panels (2 MB) = L2-resident; A fetched from HBM once total.
__launch_bounds__(256, 2)
__global__ void gemm_bf16_k(const short* __restrict__ A0, const short* __restrict__ A1, int lda,
                            const short* __restrict__ Bt0, const short* __restrict__ Bt1, int ldb,
                            short* __restrict__ C0, short* __restrict__ C1, int ldc, int K,
                            int nbCol, int nbRow) {
  __shared__ short As[128 * 64];
  __shared__ short Bs[128 * 64];

  // ---- XCD-aware bijective remap
  int orig = blockIdx.x;
  int nwg = gridDim.x;
  int q = nwg >> 3, rr = nwg & 7;
  int xcd = orig & 7, idx = orig >> 3;
  int wg = (xcd < rr ? xcd * (q + 1) : rr * (q + 1) + (xcd - rr) * q) + idx;
  int colB = wg % nbCol;
  int t2   = wg / nbCol;
  int rowB = t2 % nbRow;
  int z    = t2 / nbRow;

  const short* A  = z ? A1 : A0;
  const short* Bt = z ? Bt1 : Bt0;
  short* C        = z ? C1 : C0;

  const int tid  = threadIdx.x;
  const int lane = tid & 63;
  const int wid  = tid >> 6;
  const int wr   = wid >> 1;
  const int wc   = wid & 1;
  const int rowBase = rowB * 128;
  const int colBase = colB * 128;

  const int lrow = lane >> 3;
  const int kofs = (lane & 7) * 8;

  f32x4 acc[4][4];
#pragma unroll
  for (int m = 0; m < 4; ++m)
#pragma unroll
    for (int n = 0; n < 4; ++n)
      acc[m][n] = (f32x4){0.f, 0.f, 0.f, 0.f};

  for (int k0 = 0; k0 < K; k0 += 64) {
#pragma unroll
    for (int c = 0; c < 4; ++c) {
      int chunk = wid * 4 + c;
      int r = chunk * 8 + lrow;
      const short* g = A + (size_t)(rowBase + r) * lda + k0 + kofs;
      GLDS16(g, &As[chunk * 8 * 64]);
    }
#pragma unroll
    for (int c = 0; c < 4; ++c) {
      int chunk = wid * 4 + c;
      int r = chunk * 8 + lrow;
      const short* g = Bt + (size_t)(colBase + r) * ldb + k0 + kofs;
      GLDS16(g, &Bs[chunk * 8 * 64]);
    }
    __syncthreads();

    bf16x8 af[2][4], bfr[2][4];
#pragma unroll
    for (int kk = 0; kk < 2; ++kk) {
#pragma unroll
      for (int i = 0; i < 4; ++i) {
        int ar = wr * 64 + i * 16 + (lane & 15);
        af[kk][i]  = *(const bf16x8*)&As[ar * 64 + kk * 32 + (lane >> 4) * 8];
        int br = wc * 64 + i * 16 + (lane & 15);
        bfr[kk][i] = *(const bf16x8*)&Bs[br * 64 + kk * 32 + (lane >> 4) * 8];
      }
    }
#pragma unroll
    for (int kk = 0; kk < 2; ++kk)
#pragma unroll
      for (int m = 0; m < 4; ++m)
#pragma unroll
        for (int n = 0; n < 4; ++n)
          acc[m][n] = __builtin_amdgcn_mfma_f32_16x16x32_bf16(
              af[kk][m], bfr[kk][n], acc[m][n], 0, 0, 0);
    __syncthreads();
  }

#pragma unroll
  for (int m = 0; m < 4; ++m) {
#pragma unroll
    for (int n = 0; n < 4; ++n) {
      int row0 = rowBase + wr * 64 + m * 16 + (lane >> 4) * 4;
      int col  = colBase + wc * 64 + n * 16 + (lane & 15);
#pragma unroll
      for (int reg = 0; reg < 4; ++reg)
        C[(size_t)(row0 + reg) * ldc + col] = f2bf(acc[m][n][reg]);
    }
  }
}

// ---------------------------------------------------------------- SpMM + ReLU (z=2, RPB rows/block)
template<int TPB, int VEC, int RPB>
__launch_bounds__(TPB)
__global__ void spmm_relu_v3(const int* __restrict__ po0, const int* __restrict__ po1,
                             const int2* __restrict__ pk0, const int2* __restrict__ pk1,
                             const short* __restrict__ S0, const short* __restrict__ S1, int ldS,
                             short* __restrict__ oB0, short* __restrict__ oB1, int ldB,
                             float* __restrict__ oF0, float* __restrict__ oF1, int outCols) {
  typedef short sv __attribute__((ext_vector_type(VEC)));
  const int* poffs    = blockIdx.z ? po1 : po0;
  const int2* packed  = blockIdx.z ? pk1 : pk0;
  const short* S      = blockIdx.z ? S1 : S0;
  short* outB         = blockIdx.z ? oB1 : oB0;
  float* outF         = blockIdx.z ? oF1 : oF0;
  int c0 = threadIdx.x * VEC;

  int rEnd = blockIdx.x * RPB + RPB;
  for (int r = blockIdx.x * RPB; r < rEnd; ++r) {
    int e0 = poffs[r], e1 = poffs[r + 1];
    float acc[VEC];
#pragma unroll
    for (int j = 0; j < VEC; ++j) acc[j] = 0.f;

    for (int i = e0; i < e1; i += 4) {
      const int4* p4 = (const int4*)&packed[i];   // 32B aligned (i % 4 == 0)
      int4 a = p4[0];
      int4 b = p4[1];
      sv s0 = *(const sv*)&S[(size_t)a.x * ldS + c0];
      sv s1 = *(const sv*)&S[(size_t)a.z * ldS + c0];
      sv s2 = *(const sv*)&S[(size_t)b.x * ldS + c0];
      sv s3 = *(const sv*)&S[(size_t)b.z * ldS + c0];
      float v0 = __int_as_float(a.y);
      float v1 = __int_as_float(a.w);
      float v2 = __int_as_float(b.y);
      float v3 = __int_as_float(b.w);
#pragma unroll
      for (int j = 0; j < VEC; ++j) {
        acc[j] += v0 * bf2f(s0[j]);
        acc[j] += v1 * bf2f(s1[j]);
        acc[j] += v2 * bf2f(s2[j]);
        acc[j] += v3 * bf2f(s3[j]);
      }
    }

    if (outB) {
      sv o;
#pragma unroll
      for (int j = 0; j < VEC; ++j) o[j] = f2bf(fmaxf(acc[j], 0.f));
      *(sv*)&outB[(size_t)r * ldB + c0] = o;
    } else {
#pragma unroll
      for (int j = 0; j < VEC; ++j)
        if (c0 + j < outCols)
          outF[(size_t)r * outCols + c0 + j] = fmaxf(acc[j], 0.f);
    }
  }
}

// ---------------------------------------------------------------- row l2 norm (z=2)
__global__ void l2norm2_k(const short* __restrict__ H0, const short* __restrict__ H1, int ldH,
                          float* __restrict__ o0, float* __restrict__ o1, int cols) {
  const short* H = blockIdx.y ? H1 : H0;
  float* out = blockIdx.y ? o1 : o0;
  __shared__ float red[4];
  int r = blockIdx.x;
  int t = threadIdx.x;
  float s = 0.f;
  for (int c = t; c < ldH; c += 256) {
    float v = bf2f(H[(size_t)r * ldH + c]);
    s += v * v;
  }
  for (int off = 32; off >= 1; off >>= 1) s += __shfl_down(s, off, 64);
  if ((t & 63) == 0) red[t >> 6] = s;
  __syncthreads();
  float tot = red[0] + red[1] + red[2] + red[3];
  float inv = 1.f / fmaxf(sqrtf(tot), 1e-12f);
  for (int c = t; c < cols; c += 256)
    out[(size_t)r * cols + c] = bf2f(H[(size_t)r * ldH + c]) * inv;
}

// ---------------------------------------------------------------- launch

extern "C" void kernel_launch(void* const* d_in, const int* in_sizes, int n_in,
                              void* d_out, int out_size, void* d_ws, size_t ws_size,
                              hipStream_t stream) {
  const float* emb_sr  = (const float*)d_in[0];
  const float* emb_tg  = (const float*)d_in[1];
  const float* attr_sr = (const float*)d_in[2];
  const float* attr_tg = (const float*)d_in[3];
  const int*   row_sr  = (const int*)d_in[4];
  const int*   col_sr  = (const int*)d_in[5];
  const float* vals_sr = (const float*)d_in[6];
  const int*   row_tg  = (const int*)d_in[7];
  const int*   col_tg  = (const int*)d_in[8];
  const float* vals_tg = (const float*)d_in[9];
  const float* W_s0    = (const float*)d_in[10];
  const float* W_s1    = (const float*)d_in[11];
  const float* W_a11   = (const float*)d_in[12];
  const float* W_a12   = (const float*)d_in[13];
  const float* W_a2    = (const float*)d_in[14];

  const int N = N_NODES, Dd = D_IN, E = E_EDGES;

  char* ws = (char*)d_ws;
  size_t off = 0;
  auto alloc = [&](size_t bytes) -> void* {
    void* p = ws + off;
    off += (bytes + 255) & ~(size_t)255;
    return p;
  };
  // big ping-pong buffers, per graph
  short* X0 = (short*)alloc((size_t)MP * DP * 2);
  short* X1 = (short*)alloc((size_t)MP * DP * 2);
  short* T0 = (short*)alloc((size_t)MP * DP * 2);
  short* T1 = (short*)alloc((size_t)MP * DP * 2);
  // weights
  short* Ws0t  = (short*)alloc((size_t)DP * DP * 2);
  short* Ws1t  = (short*)alloc((size_t)DP * DP * 2);
  short* Wa11t = (short*)alloc((size_t)DAP * DP * 2);
  short* Wa12t = (short*)alloc((size_t)DAP * DP * 2);
  short* Wa2t  = (short*)alloc((size_t)DAP * DAP * 2);
  // CSR: contiguous zero region [deg0|cur0|deg1|cur1|pack0|pack1]
  int*  ibuf    = (int*)alloc((size_t)4 * N * 4);
  int2* pack_sr = (int2*)alloc((size_t)PEMAX * 8);
  int2* pack_tg = (int2*)alloc((size_t)PEMAX * 8);
  int*  poffs_sr = (int*)alloc((size_t)(N + 1) * 4);
  int*  poffs_tg = (int*)alloc((size_t)(N + 1) * 4);
  if (off > ws_size) return;

  int* deg_sr = ibuf;
  int* cur_sr = ibuf + N;
  int* deg_tg = ibuf + 2 * N;
  int* cur_tg = ibuf + 3 * N;
  const int ZERO_N = 4 * N + 2 * (PEMAX * 2);   // contiguous ints incl. both packs

  float* out_sr  = (float*)d_out;
  float* out_tg  = out_sr + (size_t)N * Dd;
  float* out_sra = out_tg + (size_t)N * Dd;
  float* out_tga = out_sra + (size_t)N * DA;

  // ---- padded-CSR build, both graphs batched
  zero_int_k<<<dim3((ZERO_N + 255) / 256), 256, 0, stream>>>(ibuf, ZERO_N);
  hist2_k<<<dim3((2 * E + 255) / 256), 256, 0, stream>>>(row_sr, row_tg, E, deg_sr, deg_tg);
  scan_pad2_k<<<2, SCAN_T, 0, stream>>>(deg_sr, deg_tg, N, poffs_sr, poffs_tg);
  scatter_pack2_k<<<dim3((2 * E + 255) / 256), 256, 0, stream>>>(
      row_sr, col_sr, vals_sr, row_tg, col_tg, vals_tg, E,
      poffs_sr, poffs_tg, cur_sr, cur_tg, pack_sr, pack_tg);

  // ---- weight conversions (transposed + padded), batched
  cvt_w_t2_k<<<dim3(DP / 256, DP, 2), 256, 0, stream>>>(W_s0, W_s1, Dd, Dd, Ws0t, Ws1t, DP);
  cvt_w_t2_k<<<dim3(DP / 256, DAP, 2), 256, 0, stream>>>(W_a11, W_a12, Dd, DA, Wa11t, Wa12t, DP);
  cvt_w_t2_k<<<dim3(1, DAP, 1), 256, 0, stream>>>(W_a2, W_a2, DA, DA, Wa2t, Wa2t, DAP);

  // ---- structural branch (both graphs batched inside GEMM)
  cvt_pad2_k<<<dim3(1, MP, 2), 256, 0, stream>>>(emb_sr, emb_tg, N, Dd, X0, X1, DP);
  gemm_bf16_k<<<dim3(8 * MBLK * 2), 256, 0, stream>>>(X0, X1, DP, Ws0t, Ws0t, DP,
                                                      T0, T1, DP, DP, 8, MBLK);
  spmm_relu_v3<128, 8, 4><<<dim3(N / 4, 1, 2), 128, 0, stream>>>(
      poffs_sr, poffs_tg, pack_sr, pack_tg, T0, T1, DP, X0, X1, DP, nullptr, nullptr, 0);
  gemm_bf16_k<<<dim3(8 * MBLK * 2), 256, 0, stream>>>(X0, X1, DP, Ws1t, Ws1t, DP,
                                                      T0, T1, DP, DP, 8, MBLK);
  spmm_relu_v3<128, 8, 4><<<dim3(N / 4, 1, 2), 128, 0, stream>>>(
      poffs_sr, poffs_tg, pack_sr, pack_tg, T0, T1, DP, X0, X1, DP, nullptr, nullptr, 0);
  l2norm2_k<<<dim3(N, 2), 256, 0, stream>>>(X0, X1, DP, out_sr, out_tg, Dd);

  // ---- attribute branch (both graphs batched inside GEMM)
  cvt_pad2_k<<<dim3(1, MP, 2), 256, 0, stream>>>(attr_sr, attr_tg, N, Dd, X0, X1, DP);
  gemm_bf16_k<<<dim3(1 * MBLK * 2), 256, 0, stream>>>(X0, X1, DP, Wa11t, Wa12t, DP,
                                                      T0, T1, DP, DP, 1, MBLK);
  spmm_relu_v3<64, 2, 4><<<dim3(N / 4, 1, 2), 64, 0, stream>>>(
      poffs_sr, poffs_tg, pack_sr, pack_tg, T0, T1, DP, X0, X1, DP, nullptr, nullptr, 0);
  gemm_bf16_k<<<dim3(1 * MBLK * 2), 256, 0, stream>>>(X0, X1, DP, Wa2t, Wa2t, DAP,
                                                      T0, T1, DP, DAP, 1, MBLK);
  spmm_relu_v3<64, 2, 4><<<dim3(N / 4, 1, 2), 64, 0, stream>>>(
      poffs_sr, poffs_tg, pack_sr, pack_tg, T0, T1, DP, nullptr, nullptr, 0, out_sra, out_tga, DA);
}

// Round 5
// 676.078 us; speedup vs baseline: 2.3725x; 1.0669x over previous
//
#include <hip/hip_runtime.h>

#define N_NODES 20000
#define D_IN    1000
#define E_EDGES 160000
#define DA      100

#define MP   20096    // 157 * 128 (padded rows)
#define DP   1024     // padded K / structural cols
#define DAP  128      // padded attr cols
#define MBLK 157
#define PEMAX (E_EDGES + 4 * N_NODES)   // padded edge capacity (rows padded to x4)

typedef __bf16 bf16x8 __attribute__((ext_vector_type(8)));
typedef float  f32x4  __attribute__((ext_vector_type(4)));

__device__ __forceinline__ short f2bf(float f) {
  __bf16 h = (__bf16)f;                 // native RNE cvt (m240: scalar cast is the fast path)
  return *(short*)&h;
}
__device__ __forceinline__ float bf2f(short s) {
  return __uint_as_float(((unsigned)(unsigned short)s) << 16);
}

#define GLDS16(g, l) __builtin_amdgcn_global_load_lds( \
    (const __attribute__((address_space(1))) void*)(g), \
    (__attribute__((address_space(3))) void*)(l), 16, 0, 0)

// ---------------------------------------------------------------- conversions

// batched (z=2) f32->bf16 pad, float4 loads. grid: (1, MP, 2), 256 thr (1024 cols)
__global__ void cvt_pad2_k(const float* __restrict__ s0, const float* __restrict__ s1,
                           int R, int C,
                           short* __restrict__ d0, short* __restrict__ d1, int Cp) {
  const float* src = blockIdx.z ? s1 : s0;
  short* dst = blockIdx.z ? d1 : d0;
  int r = blockIdx.y;
  int c0 = threadIdx.x * 4;
  short4 o = {0, 0, 0, 0};
  if (r < R) {
    if (c0 + 3 < C) {
      float4 v = *(const float4*)&src[(size_t)r * C + c0];
      o.x = f2bf(v.x); o.y = f2bf(v.y); o.z = f2bf(v.z); o.w = f2bf(v.w);
    } else {
#pragma unroll
      for (int j = 0; j < 4; ++j) {
        float v = (c0 + j < C) ? src[(size_t)r * C + c0 + j] : 0.f;
        ((short*)&o)[j] = f2bf(v);
      }
    }
  }
  *(short4*)&dst[(size_t)r * Cp + c0] = o;
}

// batched (z=2) W transpose+pad: dst[n*Kp+k] = bf16(src[k*Nc+n]). grid ((Kp+255)/256, Np, 2)
__global__ void cvt_w_t2_k(const float* __restrict__ s0, const float* __restrict__ s1,
                           int K, int Nc,
                           short* __restrict__ d0, short* __restrict__ d1, int Kp) {
  const float* src = blockIdx.z ? s1 : s0;
  short* dst = blockIdx.z ? d1 : d0;
  int n = blockIdx.y;
  int k = blockIdx.x * blockDim.x + threadIdx.x;
  if (k >= Kp) return;
  float v = (k < K && n < Nc) ? src[(size_t)k * Nc + n] : 0.f;
  dst[(size_t)n * Kp + k] = f2bf(v);
}

__global__ void zero_int_k(int* p, int n) {
  int i = blockIdx.x * blockDim.x + threadIdx.x;
  if (i < n) p[i] = 0;
}

// ---------------------------------------------------------------- CSR build (padded, both graphs)

__global__ void hist2_k(const int* __restrict__ row0, const int* __restrict__ row1, int E,
                        int* __restrict__ deg0, int* __restrict__ deg1) {
  int e = blockIdx.x * blockDim.x + threadIdx.x;
  if (e < E) atomicAdd(&deg0[row0[e]], 1);
  else if (e < 2 * E) atomicAdd(&deg1[row1[e - E]], 1);
}

#define SCAN_T 1024
#define SCAN_C 20
// exclusive scan of round_up(deg,4); grid 2 blocks (one per graph)
__launch_bounds__(SCAN_T)
__global__ void scan_pad2_k(const int* __restrict__ dg0, const int* __restrict__ dg1, int n,
                            int* __restrict__ p0, int* __restrict__ p1) {
  const int* deg = blockIdx.x ? dg1 : dg0;
  int* poffs = blockIdx.x ? p1 : p0;
  __shared__ int lds[SCAN_T];
  int t = threadIdx.x;
  int base = t * SCAN_C;
  int v[SCAN_C];
  int s = 0;
#pragma unroll
  for (int i = 0; i < SCAN_C; ++i) {
    int idx = base + i;
    int x = (idx < n) ? ((deg[idx] + 3) & ~3) : 0;
    s += x;
    v[i] = s;
  }
  lds[t] = s;
  __syncthreads();
  for (int off = 1; off < SCAN_T; off <<= 1) {
    int add = (t >= off) ? lds[t - off] : 0;
    __syncthreads();
    lds[t] += add;
    __syncthreads();
  }
  int prefix = lds[t] - s;
#pragma unroll
  for (int i = 0; i < SCAN_C; ++i) {
    int idx = base + i;
    if (idx < n) poffs[idx + 1] = v[i] + prefix;
  }
  if (t == 0) poffs[0] = 0;
}

__global__ void scatter_pack2_k(const int* __restrict__ row0, const int* __restrict__ col0,
                                const float* __restrict__ val0,
                                const int* __restrict__ row1, const int* __restrict__ col1,
                                const float* __restrict__ val1, int E,
                                const int* __restrict__ po0, const int* __restrict__ po1,
                                int* __restrict__ cur0, int* __restrict__ cur1,
                                int2* __restrict__ pk0, int2* __restrict__ pk1) {
  int e = blockIdx.x * blockDim.x + threadIdx.x;
  if (e < E) {
    int r = row0[e];
    int p = atomicAdd(&cur0[r], 1);
    pk0[po0[r] + p] = make_int2(col0[e], __float_as_int(val0[e]));
  } else if (e < 2 * E) {
    int ee = e - E;
    int r = row1[ee];
    int p = atomicAdd(&cur1[r], 1);
    pk1[po1[r] + p] = make_int2(col1[ee], __float_as_int(val1[ee]));
  }
}

// ---------------------------------------------------------------- GEMM (bf16 MFMA, z=2 batched)
// C[M x Nc] = A[M x K] * Bt[Nc x K]^T, bf16 in, f32 accum, bf16 out.
// 1-D launch with XCD-aware bijective remap (m204): each XCD gets a contiguous
// chunk (cols fastest) so its concurrent blocks share A row-panels + B panels
// in its private L2 (r4: FETCH 325 -> 74 MB).
__launch_bounds__(256, 2)
__global__ void gemm_bf16_k(const short* __restrict__ A0, const short* __restrict__ A1, int lda,
                            const short* __restrict__ Bt0, const short* __restrict__ Bt1, int ldb,
                            short* __restrict__ C0, short* __restrict__ C1, int ldc, int K,
                            int nbCol, int nbRow) {
  __shared__ short As[128 * 64];
  __shared__ short Bs[128 * 64];

  // ---- XCD-aware bijective remap
  int orig = blockIdx.x;
  int nwg = gridDim.x;
  int q = nwg >> 3, rr = nwg & 7;
  int xcd = orig & 7, idx = orig >> 3;
  int wg = (xcd < rr ? xcd * (q + 1) : rr * (q + 1) + (xcd - rr) * q) + idx;
  int colB = wg % nbCol;
  int t2   = wg / nbCol;
  int rowB = t2 % nbRow;
  int z    = t2 / nbRow;

  const short* A  = z ? A1 : A0;
  const short* Bt = z ? Bt1 : Bt0;
  short* C        = z ? C1 : C0;

  const int tid  = threadIdx.x;
  const int lane = tid & 63;
  const int wid  = tid >> 6;
  const int wr   = wid >> 1;
  const int wc   = wid & 1;
  const int rowBase = rowB * 128;
  const int colBase = colB * 128;

  const int lrow = lane >> 3;
  const int kofs = (lane & 7) * 8;

  f32x4 acc[4][4];
#pragma unroll
  for (int m = 0; m < 4; ++m)
#pragma unroll
    for (int n = 0; n < 4; ++n)
      acc[m][n] = (f32x4){0.f, 0.f, 0.f, 0.f};

  for (int k0 = 0; k0 < K; k0 += 64) {
#pragma unroll
    for (int c = 0; c < 4; ++c) {
      int chunk = wid * 4 + c;
      int r = chunk * 8 + lrow;
      const short* g = A + (size_t)(rowBase + r) * lda + k0 + kofs;
      GLDS16(g, &As[chunk * 8 * 64]);
    }
#pragma unroll
    for (int c = 0; c < 4; ++c) {
      int chunk = wid * 4 + c;
      int r = chunk * 8 + lrow;
      const short* g = Bt + (size_t)(colBase + r) * ldb + k0 + kofs;
      GLDS16(g, &Bs[chunk * 8 * 64]);
    }
    __syncthreads();

    bf16x8 af[2][4], bfr[2][4];
#pragma unroll
    for (int kk = 0; kk < 2; ++kk) {
#pragma unroll
      for (int i = 0; i < 4; ++i) {
        int ar = wr * 64 + i * 16 + (lane & 15);
        af[kk][i]  = *(const bf16x8*)&As[ar * 64 + kk * 32 + (lane >> 4) * 8];
        int br = wc * 64 + i * 16 + (lane & 15);
        bfr[kk][i] = *(const bf16x8*)&Bs[br * 64 + kk * 32 + (lane >> 4) * 8];
      }
    }
#pragma unroll
    for (int kk = 0; kk < 2; ++kk)
#pragma unroll
      for (int m = 0; m < 4; ++m)
#pragma unroll
        for (int n = 0; n < 4; ++n)
          acc[m][n] = __builtin_amdgcn_mfma_f32_16x16x32_bf16(
              af[kk][m], bfr[kk][n], acc[m][n], 0, 0, 0);
    __syncthreads();
  }

#pragma unroll
  for (int m = 0; m < 4; ++m) {
#pragma unroll
    for (int n = 0; n < 4; ++n) {
      int row0 = rowBase + wr * 64 + m * 16 + (lane >> 4) * 4;
      int col  = colBase + wc * 64 + n * 16 + (lane & 15);
#pragma unroll
      for (int reg = 0; reg < 4; ++reg)
        C[(size_t)(row0 + reg) * ldc + col] = f2bf(acc[m][n][reg]);
    }
  }
}

// ---------------------------------------------------------------- SpMM + ReLU (z=2, RPB rows/block)
// MODE 0: write bf16 to outB (all VEC cols). MODE 1: write f32 to outF (c<outCols).
// MODE 2: fused row-l2norm -> f32 outF (c<outCols), stride outCols.
template<int TPB, int VEC, int RPB, int MODE>
__launch_bounds__(TPB)
__global__ void spmm_v4(const int* __restrict__ po0, const int* __restrict__ po1,
                        const int2* __restrict__ pk0, const int2* __restrict__ pk1,
                        const short* __restrict__ S0, const short* __restrict__ S1, int ldS,
                        short* __restrict__ oB0, short* __restrict__ oB1, int ldB,
                        float* __restrict__ oF0, float* __restrict__ oF1, int outCols) {
  typedef short sv __attribute__((ext_vector_type(VEC)));
  const int* poffs    = blockIdx.z ? po1 : po0;
  const int2* packed  = blockIdx.z ? pk1 : pk0;
  const short* S      = blockIdx.z ? S1 : S0;
  short* outB         = blockIdx.z ? oB1 : oB0;
  float* outF         = blockIdx.z ? oF1 : oF0;
  __shared__ float red[TPB / 64 > 0 ? TPB / 64 : 1];
  const int lane = threadIdx.x & 63;
  const int wv   = threadIdx.x >> 6;
  int c0 = threadIdx.x * VEC;

  int rEnd = blockIdx.x * RPB + RPB;
  for (int r = blockIdx.x * RPB; r < rEnd; ++r) {
    int e0 = poffs[r], e1 = poffs[r + 1];
    float acc[VEC];
#pragma unroll
    for (int j = 0; j < VEC; ++j) acc[j] = 0.f;

    for (int i = e0; i < e1; i += 4) {
      const int4* p4 = (const int4*)&packed[i];   // 32B aligned (i % 4 == 0)
      int4 a = p4[0];
      int4 b = p4[1];
      sv s0 = *(const sv*)&S[(size_t)a.x * ldS + c0];
      sv s1 = *(const sv*)&S[(size_t)a.z * ldS + c0];
      sv s2 = *(const sv*)&S[(size_t)b.x * ldS + c0];
      sv s3 = *(const sv*)&S[(size_t)b.z * ldS + c0];
      float v0 = __int_as_float(a.y);
      float v1 = __int_as_float(a.w);
      float v2 = __int_as_float(b.y);
      float v3 = __int_as_float(b.w);
#pragma unroll
      for (int j = 0; j < VEC; ++j) {
        acc[j] += v0 * bf2f(s0[j]);
        acc[j] += v1 * bf2f(s1[j]);
        acc[j] += v2 * bf2f(s2[j]);
        acc[j] += v3 * bf2f(s3[j]);
      }
    }
#pragma unroll
    for (int j = 0; j < VEC; ++j) acc[j] = fmaxf(acc[j], 0.f);

    if (MODE == 0) {
      sv o;
#pragma unroll
      for (int j = 0; j < VEC; ++j) o[j] = f2bf(acc[j]);
      *(sv*)&outB[(size_t)r * ldB + c0] = o;
    } else if (MODE == 1) {
#pragma unroll
      for (int j = 0; j < VEC; ++j)
        if (c0 + j < outCols)
          outF[(size_t)r * outCols + c0 + j] = acc[j];
    } else {
      // fused l2norm: padded cols are exactly 0, so they don't affect the norm
      float ss = 0.f;
#pragma unroll
      for (int j = 0; j < VEC; ++j) ss += acc[j] * acc[j];
      for (int off = 32; off >= 1; off >>= 1) ss += __shfl_down(ss, off, 64);
      if (lane == 0) red[wv] = ss;
      __syncthreads();
      float tot = 0.f;
#pragma unroll
      for (int w = 0; w < TPB / 64; ++w) tot += red[w];
      float inv = 1.f / fmaxf(sqrtf(tot), 1e-12f);
#pragma unroll
      for (int j = 0; j < VEC; ++j)
        if (c0 + j < outCols)
          outF[(size_t)r * outCols + c0 + j] = acc[j] * inv;
      __syncthreads();   // red[] reused next row
    }
  }
}

// ---------------------------------------------------------------- launch

extern "C" void kernel_launch(void* const* d_in, const int* in_sizes, int n_in,
                              void* d_out, int out_size, void* d_ws, size_t ws_size,
                              hipStream_t stream) {
  const float* emb_sr  = (const float*)d_in[0];
  const float* emb_tg  = (const float*)d_in[1];
  const float* attr_sr = (const float*)d_in[2];
  const float* attr_tg = (const float*)d_in[3];
  const int*   row_sr  = (const int*)d_in[4];
  const int*   col_sr  = (const int*)d_in[5];
  const float* vals_sr = (const float*)d_in[6];
  const int*   row_tg  = (const int*)d_in[7];
  const int*   col_tg  = (const int*)d_in[8];
  const float* vals_tg = (const float*)d_in[9];
  const float* W_s0    = (const float*)d_in[10];
  const float* W_s1    = (const float*)d_in[11];
  const float* W_a11   = (const float*)d_in[12];
  const float* W_a12   = (const float*)d_in[13];
  const float* W_a2    = (const float*)d_in[14];

  const int N = N_NODES, Dd = D_IN, E = E_EDGES;

  char* ws = (char*)d_ws;
  size_t off = 0;
  auto alloc = [&](size_t bytes) -> void* {
    void* p = ws + off;
    off += (bytes + 255) & ~(size_t)255;
    return p;
  };
  // big ping-pong buffers, per graph
  short* X0 = (short*)alloc((size_t)MP * DP * 2);
  short* X1 = (short*)alloc((size_t)MP * DP * 2);
  short* T0 = (short*)alloc((size_t)MP * DP * 2);
  short* T1 = (short*)alloc((size_t)MP * DP * 2);
  // weights
  short* Ws0t  = (short*)alloc((size_t)DP * DP * 2);
  short* Ws1t  = (short*)alloc((size_t)DP * DP * 2);
  short* Wa11t = (short*)alloc((size_t)DAP * DP * 2);
  short* Wa12t = (short*)alloc((size_t)DAP * DP * 2);
  short* Wa2t  = (short*)alloc((size_t)DAP * DAP * 2);
  // CSR: contiguous zero region [deg0|cur0|deg1|cur1|pack0|pack1]
  int*  ibuf    = (int*)alloc((size_t)4 * N * 4);
  int2* pack_sr = (int2*)alloc((size_t)PEMAX * 8);
  int2* pack_tg = (int2*)alloc((size_t)PEMAX * 8);
  int*  poffs_sr = (int*)alloc((size_t)(N + 1) * 4);
  int*  poffs_tg = (int*)alloc((size_t)(N + 1) * 4);
  if (off > ws_size) return;

  int* deg_sr = ibuf;
  int* cur_sr = ibuf + N;
  int* deg_tg = ibuf + 2 * N;
  int* cur_tg = ibuf + 3 * N;
  const int ZERO_N = 4 * N + 2 * (PEMAX * 2);   // contiguous ints incl. both packs

  float* out_sr  = (float*)d_out;
  float* out_tg  = out_sr + (size_t)N * Dd;
  float* out_sra = out_tg + (size_t)N * Dd;
  float* out_tga = out_sra + (size_t)N * DA;

  // ---- padded-CSR build, both graphs batched
  zero_int_k<<<dim3((ZERO_N + 255) / 256), 256, 0, stream>>>(ibuf, ZERO_N);
  hist2_k<<<dim3((2 * E + 255) / 256), 256, 0, stream>>>(row_sr, row_tg, E, deg_sr, deg_tg);
  scan_pad2_k<<<2, SCAN_T, 0, stream>>>(deg_sr, deg_tg, N, poffs_sr, poffs_tg);
  scatter_pack2_k<<<dim3((2 * E + 255) / 256), 256, 0, stream>>>(
      row_sr, col_sr, vals_sr, row_tg, col_tg, vals_tg, E,
      poffs_sr, poffs_tg, cur_sr, cur_tg, pack_sr, pack_tg);

  // ---- weight conversions (transposed + padded), batched
  cvt_w_t2_k<<<dim3(DP / 256, DP, 2), 256, 0, stream>>>(W_s0, W_s1, Dd, Dd, Ws0t, Ws1t, DP);
  cvt_w_t2_k<<<dim3(DP / 256, DAP, 2), 256, 0, stream>>>(W_a11, W_a12, Dd, DA, Wa11t, Wa12t, DP);
  cvt_w_t2_k<<<dim3(1, DAP, 1), 256, 0, stream>>>(W_a2, W_a2, DA, DA, Wa2t, Wa2t, DAP);

  // ---- structural branch (both graphs batched inside GEMM)
  cvt_pad2_k<<<dim3(1, MP, 2), 256, 0, stream>>>(emb_sr, emb_tg, N, Dd, X0, X1, DP);
  gemm_bf16_k<<<dim3(8 * MBLK * 2), 256, 0, stream>>>(X0, X1, DP, Ws0t, Ws0t, DP,
                                                      T0, T1, DP, DP, 8, MBLK);
  spmm_v4<128, 8, 4, 0><<<dim3(N / 4, 1, 2), 128, 0, stream>>>(
      poffs_sr, poffs_tg, pack_sr, pack_tg, T0, T1, DP, X0, X1, DP, nullptr, nullptr, 0);
  gemm_bf16_k<<<dim3(8 * MBLK * 2), 256, 0, stream>>>(X0, X1, DP, Ws1t, Ws1t, DP,
                                                      T0, T1, DP, DP, 8, MBLK);
  // spmm #2 with fused l2norm -> f32 out (stride Dd)
  spmm_v4<128, 8, 4, 2><<<dim3(N / 4, 1, 2), 128, 0, stream>>>(
      poffs_sr, poffs_tg, pack_sr, pack_tg, T0, T1, DP, nullptr, nullptr, 0, out_sr, out_tg, Dd);

  // ---- attribute branch (compact stride DAP after first GEMM)
  cvt_pad2_k<<<dim3(1, MP, 2), 256, 0, stream>>>(attr_sr, attr_tg, N, Dd, X0, X1, DP);
  gemm_bf16_k<<<dim3(1 * MBLK * 2), 256, 0, stream>>>(X0, X1, DP, Wa11t, Wa12t, DP,
                                                      T0, T1, DAP, DP, 1, MBLK);
  spmm_v4<64, 2, 4, 0><<<dim3(N / 4, 1, 2), 64, 0, stream>>>(
      poffs_sr, poffs_tg, pack_sr, pack_tg, T0, T1, DAP, X0, X1, DAP, nullptr, nullptr, 0);
  gemm_bf16_k<<<dim3(1 * MBLK * 2), 256, 0, stream>>>(X0, X1, DAP, Wa2t, Wa2t, DAP,
                                                      T0, T1, DAP, DAP, 1, MBLK);
  spmm_v4<64, 2, 4, 1><<<dim3(N / 4, 1, 2), 64, 0, stream>>>(
      poffs_sr, poffs_tg, pack_sr, pack_tg, T0, T1, DAP, nullptr, nullptr, 0, out_sra, out_tga, DA);
}

// Round 6
// 636.226 us; speedup vs baseline: 2.5212x; 1.0626x over previous
//
#include <hip/hip_runtime.h>

#define N_NODES 20000
#define D_IN    1000
#define E_EDGES 160000
#define DA      100

#define MP   20096    // 157 * 128 (padded rows)
#define DP   1024     // padded K / structural cols
#define DAP  128      // padded attr cols
#define MBLK 157
#define NRB  1250     // row-blocks per graph for spmm (16 rows/block)
#define PEMAX (E_EDGES + 4 * N_NODES)   // padded edge capacity (rows padded to x4)

typedef __bf16 bf16x8 __attribute__((ext_vector_type(8)));
typedef float  f32x4  __attribute__((ext_vector_type(4)));
typedef short  short8v __attribute__((ext_vector_type(8)));

__device__ __forceinline__ short f2bf(float f) {
  __bf16 h = (__bf16)f;                 // native RNE cvt
  return *(short*)&h;
}
__device__ __forceinline__ float bf2f(short s) {
  return __uint_as_float(((unsigned)(unsigned short)s) << 16);
}

#define GLDS16(g, l) __builtin_amdgcn_global_load_lds( \
    (const __attribute__((address_space(1))) void*)(g), \
    (__attribute__((address_space(3))) void*)(l), 16, 0, 0)

// ---------------------------------------------------------------- conversions

// batched (z=2) f32->bf16 pad, float4 loads. grid: (1, MP, 2), 256 thr (1024 cols)
__global__ void cvt_pad2_k(const float* __restrict__ s0, const float* __restrict__ s1,
                           int R, int C,
                           short* __restrict__ d0, short* __restrict__ d1, int Cp) {
  const float* src = blockIdx.z ? s1 : s0;
  short* dst = blockIdx.z ? d1 : d0;
  int r = blockIdx.y;
  int c0 = threadIdx.x * 4;
  short4 o = {0, 0, 0, 0};
  if (r < R) {
    if (c0 + 3 < C) {
      float4 v = *(const float4*)&src[(size_t)r * C + c0];
      o.x = f2bf(v.x); o.y = f2bf(v.y); o.z = f2bf(v.z); o.w = f2bf(v.w);
    } else {
#pragma unroll
      for (int j = 0; j < 4; ++j) {
        float v = (c0 + j < C) ? src[(size_t)r * C + c0 + j] : 0.f;
        ((short*)&o)[j] = f2bf(v);
      }
    }
  }
  *(short4*)&dst[(size_t)r * Cp + c0] = o;
}

// batched (z=2) W transpose+pad: dst[n*Kp+k] = bf16(src[k*Nc+n]). grid ((Kp+255)/256, Np, 2)
__global__ void cvt_w_t2_k(const float* __restrict__ s0, const float* __restrict__ s1,
                           int K, int Nc,
                           short* __restrict__ d0, short* __restrict__ d1, int Kp) {
  const float* src = blockIdx.z ? s1 : s0;
  short* dst = blockIdx.z ? d1 : d0;
  int n = blockIdx.y;
  int k = blockIdx.x * blockDim.x + threadIdx.x;
  if (k >= Kp) return;
  float v = (k < K && n < Nc) ? src[(size_t)k * Nc + n] : 0.f;
  dst[(size_t)n * Kp + k] = f2bf(v);
}

__global__ void zero_int_k(int* p, int n) {
  int i = blockIdx.x * blockDim.x + threadIdx.x;
  if (i < n) p[i] = 0;
}

// ---------------------------------------------------------------- CSR build (padded, both graphs)

__global__ void hist2_k(const int* __restrict__ row0, const int* __restrict__ row1, int E,
                        int* __restrict__ deg0, int* __restrict__ deg1) {
  int e = blockIdx.x * blockDim.x + threadIdx.x;
  if (e < E) atomicAdd(&deg0[row0[e]], 1);
  else if (e < 2 * E) atomicAdd(&deg1[row1[e - E]], 1);
}

#define SCAN_T 1024
#define SCAN_C 20
// exclusive scan of round_up(deg,4); grid 2 blocks (one per graph)
__launch_bounds__(SCAN_T)
__global__ void scan_pad2_k(const int* __restrict__ dg0, const int* __restrict__ dg1, int n,
                            int* __restrict__ p0, int* __restrict__ p1) {
  const int* deg = blockIdx.x ? dg1 : dg0;
  int* poffs = blockIdx.x ? p1 : p0;
  __shared__ int lds[SCAN_T];
  int t = threadIdx.x;
  int base = t * SCAN_C;
  int v[SCAN_C];
  int s = 0;
#pragma unroll
  for (int i = 0; i < SCAN_C; ++i) {
    int idx = base + i;
    int x = (idx < n) ? ((deg[idx] + 3) & ~3) : 0;
    s += x;
    v[i] = s;
  }
  lds[t] = s;
  __syncthreads();
  for (int off = 1; off < SCAN_T; off <<= 1) {
    int add = (t >= off) ? lds[t - off] : 0;
    __syncthreads();
    lds[t] += add;
    __syncthreads();
  }
  int prefix = lds[t] - s;
#pragma unroll
  for (int i = 0; i < SCAN_C; ++i) {
    int idx = base + i;
    if (idx < n) poffs[idx + 1] = v[i] + prefix;
  }
  if (t == 0) poffs[0] = 0;
}

__global__ void scatter_pack2_k(const int* __restrict__ row0, const int* __restrict__ col0,
                                const float* __restrict__ val0,
                                const int* __restrict__ row1, const int* __restrict__ col1,
                                const float* __restrict__ val1, int E,
                                const int* __restrict__ po0, const int* __restrict__ po1,
                                int* __restrict__ cur0, int* __restrict__ cur1,
                                int2* __restrict__ pk0, int2* __restrict__ pk1) {
  int e = blockIdx.x * blockDim.x + threadIdx.x;
  if (e < E) {
    int r = row0[e];
    int p = atomicAdd(&cur0[r], 1);
    pk0[po0[r] + p] = make_int2(col0[e], __float_as_int(val0[e]));
  } else if (e < 2 * E) {
    int ee = e - E;
    int r = row1[ee];
    int p = atomicAdd(&cur1[r], 1);
    pk1[po1[r] + p] = make_int2(col1[ee], __float_as_int(val1[ee]));
  }
}

// ---------------------------------------------------------------- GEMM (bf16 MFMA, z=2 batched)
// C[M x Nc] = A[M x K] * Bt[Nc x K]^T, bf16 in, f32 accum, bf16 out.
// XCD-aware bijective remap (m204); r4: FETCH 325 -> 74 MB.
__launch_bounds__(256, 2)
__global__ void gemm_bf16_k(const short* __restrict__ A0, const short* __restrict__ A1, int lda,
                            const short* __restrict__ Bt0, const short* __restrict__ Bt1, int ldb,
                            short* __restrict__ C0, short* __restrict__ C1, int ldc, int K,
                            int nbCol, int nbRow) {
  __shared__ short As[128 * 64];
  __shared__ short Bs[128 * 64];

  int orig = blockIdx.x;
  int nwg = gridDim.x;
  int q = nwg >> 3, rr = nwg & 7;
  int xcd = orig & 7, idx = orig >> 3;
  int wg = (xcd < rr ? xcd * (q + 1) : rr * (q + 1) + (xcd - rr) * q) + idx;
  int colB = wg % nbCol;
  int t2   = wg / nbCol;
  int rowB = t2 % nbRow;
  int z    = t2 / nbRow;

  const short* A  = z ? A1 : A0;
  const short* Bt = z ? Bt1 : Bt0;
  short* C        = z ? C1 : C0;

  const int tid  = threadIdx.x;
  const int lane = tid & 63;
  const int wid  = tid >> 6;
  const int wr   = wid >> 1;
  const int wc   = wid & 1;
  const int rowBase = rowB * 128;
  const int colBase = colB * 128;

  const int lrow = lane >> 3;
  const int kofs = (lane & 7) * 8;

  f32x4 acc[4][4];
#pragma unroll
  for (int m = 0; m < 4; ++m)
#pragma unroll
    for (int n = 0; n < 4; ++n)
      acc[m][n] = (f32x4){0.f, 0.f, 0.f, 0.f};

  for (int k0 = 0; k0 < K; k0 += 64) {
#pragma unroll
    for (int c = 0; c < 4; ++c) {
      int chunk = wid * 4 + c;
      int r = chunk * 8 + lrow;
      const short* g = A + (size_t)(rowBase + r) * lda + k0 + kofs;
      GLDS16(g, &As[chunk * 8 * 64]);
    }
#pragma unroll
    for (int c = 0; c < 4; ++c) {
      int chunk = wid * 4 + c;
      int r = chunk * 8 + lrow;
      const short* g = Bt + (size_t)(colBase + r) * ldb + k0 + kofs;
      GLDS16(g, &Bs[chunk * 8 * 64]);
    }
    __syncthreads();

    bf16x8 af[2][4], bfr[2][4];
#pragma unroll
    for (int kk = 0; kk < 2; ++kk) {
#pragma unroll
      for (int i = 0; i < 4; ++i) {
        int ar = wr * 64 + i * 16 + (lane & 15);
        af[kk][i]  = *(const bf16x8*)&As[ar * 64 + kk * 32 + (lane >> 4) * 8];
        int br = wc * 64 + i * 16 + (lane & 15);
        bfr[kk][i] = *(const bf16x8*)&Bs[br * 64 + kk * 32 + (lane >> 4) * 8];
      }
    }
#pragma unroll
    for (int kk = 0; kk < 2; ++kk)
#pragma unroll
      for (int m = 0; m < 4; ++m)
#pragma unroll
        for (int n = 0; n < 4; ++n)
          acc[m][n] = __builtin_amdgcn_mfma_f32_16x16x32_bf16(
              af[kk][m], bfr[kk][n], acc[m][n], 0, 0, 0);
    __syncthreads();
  }

#pragma unroll
  for (int m = 0; m < 4; ++m) {
#pragma unroll
    for (int n = 0; n < 4; ++n) {
      int row0 = rowBase + wr * 64 + m * 16 + (lane >> 4) * 4;
      int col  = colBase + wc * 64 + n * 16 + (lane & 15);
#pragma unroll
      for (int reg = 0; reg < 4; ++reg)
        C[(size_t)(row0 + reg) * ldc + col] = f2bf(acc[m][n][reg]);
    }
  }
}

// ---------------------------------------------------------------- SpMM + ReLU (v5: col-chunked, XCD-pinned)
// 16 threads/row x 8 cols (bf16x8) = 128 cols per chunk; 16 rows per 256-thr block.
// NCHUNK=8 (structural, 1024 cols): chunk = blockIdx&7 -> pinned to one XCD,
// whose L2 keeps the 5 MB column slice resident.  NCHUNK=1 (attr, 128 cols).
// MODE 0: bf16 out (stride ldB).  MODE 1: f32 out, cols < outCols (stride outCols).
template<int NCHUNK, int MODE>
__launch_bounds__(256)
__global__ void spmm_v5(const int* __restrict__ po0, const int* __restrict__ po1,
                        const int2* __restrict__ pk0, const int2* __restrict__ pk1,
                        const short* __restrict__ S0, const short* __restrict__ S1, int ldS,
                        short* __restrict__ oB0, short* __restrict__ oB1, int ldB,
                        float* __restrict__ oF0, float* __restrict__ oF1, int outCols) {
  int orig = blockIdx.x;
  int chunk, graph, rowBlk;
  if (NCHUNK == 8) {
    chunk = orig & 7;            // chunk == XCD (round-robin dispatch, verified r4)
    int idx = orig >> 3;         // [0, 2*NRB): graph-major so one slice hot at a time
    graph = idx / NRB;
    rowBlk = idx - graph * NRB;
  } else {
    chunk = 0;
    graph = orig / NRB;
    rowBlk = orig - graph * NRB;
  }
  const int* poffs   = graph ? po1 : po0;
  const int2* packed = graph ? pk1 : pk0;
  const short* S     = graph ? S1 : S0;
  short* outB        = graph ? oB1 : oB0;
  float* outF        = graph ? oF1 : oF0;

  const int lane16 = threadIdx.x & 15;
  const int rowloc = threadIdx.x >> 4;
  const int r  = rowBlk * 16 + rowloc;        // NRB*16 == 20000 exactly
  const int c0 = chunk * 128 + lane16 * 8;

  int e0 = poffs[r], e1 = poffs[r + 1];
  float acc[8];
#pragma unroll
  for (int j = 0; j < 8; ++j) acc[j] = 0.f;

  for (int i = e0; i < e1; i += 4) {
    const int4* p4 = (const int4*)&packed[i];   // same addr across 16 lanes -> broadcast
    int4 a = p4[0];
    int4 b = p4[1];
    short8v s0 = *(const short8v*)&S[(size_t)a.x * ldS + c0];
    short8v s1 = *(const short8v*)&S[(size_t)a.z * ldS + c0];
    short8v s2 = *(const short8v*)&S[(size_t)b.x * ldS + c0];
    short8v s3 = *(const short8v*)&S[(size_t)b.z * ldS + c0];
    float v0 = __int_as_float(a.y);
    float v1 = __int_as_float(a.w);
    float v2 = __int_as_float(b.y);
    float v3 = __int_as_float(b.w);
#pragma unroll
    for (int j = 0; j < 8; ++j) {
      acc[j] += v0 * bf2f(s0[j]);
      acc[j] += v1 * bf2f(s1[j]);
      acc[j] += v2 * bf2f(s2[j]);
      acc[j] += v3 * bf2f(s3[j]);
    }
  }
#pragma unroll
  for (int j = 0; j < 8; ++j) acc[j] = fmaxf(acc[j], 0.f);

  if (MODE == 0) {
    short8v o;
#pragma unroll
    for (int j = 0; j < 8; ++j) o[j] = f2bf(acc[j]);
    *(short8v*)&outB[(size_t)r * ldB + c0] = o;
  } else {
#pragma unroll
    for (int j = 0; j < 8; ++j)
      if (c0 + j < outCols)
        outF[(size_t)r * outCols + c0 + j] = acc[j];
  }
}

// ---------------------------------------------------------------- row l2 norm (z=2)
__global__ void l2norm2_k(const short* __restrict__ H0, const short* __restrict__ H1, int ldH,
                          float* __restrict__ o0, float* __restrict__ o1, int cols) {
  const short* H = blockIdx.y ? H1 : H0;
  float* out = blockIdx.y ? o1 : o0;
  __shared__ float red[4];
  int r = blockIdx.x;
  int t = threadIdx.x;
  float s = 0.f;
  for (int c = t; c < ldH; c += 256) {
    float v = bf2f(H[(size_t)r * ldH + c]);
    s += v * v;
  }
  for (int off = 32; off >= 1; off >>= 1) s += __shfl_down(s, off, 64);
  if ((t & 63) == 0) red[t >> 6] = s;
  __syncthreads();
  float tot = red[0] + red[1] + red[2] + red[3];
  float inv = 1.f / fmaxf(sqrtf(tot), 1e-12f);
  for (int c = t; c < cols; c += 256)
    out[(size_t)r * cols + c] = bf2f(H[(size_t)r * ldH + c]) * inv;
}

// ---------------------------------------------------------------- launch

extern "C" void kernel_launch(void* const* d_in, const int* in_sizes, int n_in,
                              void* d_out, int out_size, void* d_ws, size_t ws_size,
                              hipStream_t stream) {
  const float* emb_sr  = (const float*)d_in[0];
  const float* emb_tg  = (const float*)d_in[1];
  const float* attr_sr = (const float*)d_in[2];
  const float* attr_tg = (const float*)d_in[3];
  const int*   row_sr  = (const int*)d_in[4];
  const int*   col_sr  = (const int*)d_in[5];
  const float* vals_sr = (const float*)d_in[6];
  const int*   row_tg  = (const int*)d_in[7];
  const int*   col_tg  = (const int*)d_in[8];
  const float* vals_tg = (const float*)d_in[9];
  const float* W_s0    = (const float*)d_in[10];
  const float* W_s1    = (const float*)d_in[11];
  const float* W_a11   = (const float*)d_in[12];
  const float* W_a12   = (const float*)d_in[13];
  const float* W_a2    = (const float*)d_in[14];

  const int N = N_NODES, Dd = D_IN, E = E_EDGES;

  char* ws = (char*)d_ws;
  size_t off = 0;
  auto alloc = [&](size_t bytes) -> void* {
    void* p = ws + off;
    off += (bytes + 255) & ~(size_t)255;
    return p;
  };
  short* X0 = (short*)alloc((size_t)MP * DP * 2);
  short* X1 = (short*)alloc((size_t)MP * DP * 2);
  short* T0 = (short*)alloc((size_t)MP * DP * 2);
  short* T1 = (short*)alloc((size_t)MP * DP * 2);
  short* Ws0t  = (short*)alloc((size_t)DP * DP * 2);
  short* Ws1t  = (short*)alloc((size_t)DP * DP * 2);
  short* Wa11t = (short*)alloc((size_t)DAP * DP * 2);
  short* Wa12t = (short*)alloc((size_t)DAP * DP * 2);
  short* Wa2t  = (short*)alloc((size_t)DAP * DAP * 2);
  int*  ibuf    = (int*)alloc((size_t)4 * N * 4);
  int2* pack_sr = (int2*)alloc((size_t)PEMAX * 8);
  int2* pack_tg = (int2*)alloc((size_t)PEMAX * 8);
  int*  poffs_sr = (int*)alloc((size_t)(N + 1) * 4);
  int*  poffs_tg = (int*)alloc((size_t)(N + 1) * 4);
  if (off > ws_size) return;

  int* deg_sr = ibuf;
  int* cur_sr = ibuf + N;
  int* deg_tg = ibuf + 2 * N;
  int* cur_tg = ibuf + 3 * N;
  const int ZERO_N = 4 * N + 2 * (PEMAX * 2);

  float* out_sr  = (float*)d_out;
  float* out_tg  = out_sr + (size_t)N * Dd;
  float* out_sra = out_tg + (size_t)N * Dd;
  float* out_tga = out_sra + (size_t)N * DA;

  // ---- padded-CSR build, both graphs batched
  zero_int_k<<<dim3((ZERO_N + 255) / 256), 256, 0, stream>>>(ibuf, ZERO_N);
  hist2_k<<<dim3((2 * E + 255) / 256), 256, 0, stream>>>(row_sr, row_tg, E, deg_sr, deg_tg);
  scan_pad2_k<<<2, SCAN_T, 0, stream>>>(deg_sr, deg_tg, N, poffs_sr, poffs_tg);
  scatter_pack2_k<<<dim3((2 * E + 255) / 256), 256, 0, stream>>>(
      row_sr, col_sr, vals_sr, row_tg, col_tg, vals_tg, E,
      poffs_sr, poffs_tg, cur_sr, cur_tg, pack_sr, pack_tg);

  // ---- weight conversions (transposed + padded), batched
  cvt_w_t2_k<<<dim3(DP / 256, DP, 2), 256, 0, stream>>>(W_s0, W_s1, Dd, Dd, Ws0t, Ws1t, DP);
  cvt_w_t2_k<<<dim3(DP / 256, DAP, 2), 256, 0, stream>>>(W_a11, W_a12, Dd, DA, Wa11t, Wa12t, DP);
  cvt_w_t2_k<<<dim3(1, DAP, 1), 256, 0, stream>>>(W_a2, W_a2, DA, DA, Wa2t, Wa2t, DAP);

  // ---- structural branch
  cvt_pad2_k<<<dim3(1, MP, 2), 256, 0, stream>>>(emb_sr, emb_tg, N, Dd, X0, X1, DP);
  gemm_bf16_k<<<dim3(8 * MBLK * 2), 256, 0, stream>>>(X0, X1, DP, Ws0t, Ws0t, DP,
                                                      T0, T1, DP, DP, 8, MBLK);
  spmm_v5<8, 0><<<dim3(8 * 2 * NRB), 256, 0, stream>>>(
      poffs_sr, poffs_tg, pack_sr, pack_tg, T0, T1, DP, X0, X1, DP, nullptr, nullptr, 0);
  gemm_bf16_k<<<dim3(8 * MBLK * 2), 256, 0, stream>>>(X0, X1, DP, Ws1t, Ws1t, DP,
                                                      T0, T1, DP, DP, 8, MBLK);
  spmm_v5<8, 0><<<dim3(8 * 2 * NRB), 256, 0, stream>>>(
      poffs_sr, poffs_tg, pack_sr, pack_tg, T0, T1, DP, X0, X1, DP, nullptr, nullptr, 0);
  l2norm2_k<<<dim3(N, 2), 256, 0, stream>>>(X0, X1, DP, out_sr, out_tg, Dd);

  // ---- attribute branch (compact stride DAP after first GEMM)
  cvt_pad2_k<<<dim3(1, MP, 2), 256, 0, stream>>>(attr_sr, attr_tg, N, Dd, X0, X1, DP);
  gemm_bf16_k<<<dim3(1 * MBLK * 2), 256, 0, stream>>>(X0, X1, DP, Wa11t, Wa12t, DP,
                                                      T0, T1, DAP, DP, 1, MBLK);
  spmm_v5<1, 0><<<dim3(2 * NRB), 256, 0, stream>>>(
      poffs_sr, poffs_tg, pack_sr, pack_tg, T0, T1, DAP, X0, X1, DAP, nullptr, nullptr, 0);
  gemm_bf16_k<<<dim3(1 * MBLK * 2), 256, 0, stream>>>(X0, X1, DAP, Wa2t, Wa2t, DAP,
                                                      T0, T1, DAP, DAP, 1, MBLK);
  spmm_v5<1, 1><<<dim3(2 * NRB), 256, 0, stream>>>(
      poffs_sr, poffs_tg, pack_sr, pack_tg, T0, T1, DAP, nullptr, nullptr, 0, out_sra, out_tga, DA);
}